// Round 9
// baseline (1928.161 us; speedup 1.0000x reference)
//
#include <hip/hip_runtime.h>

#define H_ 1024
#define B_ 128
#define S_ 512
#define V_ 128
#define E_ 256

// LDS layout (bytes)
// Zsh: [8 w8][16 row][33 hu-slots][4 gates] f32  (pad 33 breaks bank aliasing)
// tsh: [128 v][33 hu-slots][4 gates] f32
#define ZSH_OFF 0            // 67584
#define TSH_OFF 67584        // 67584
#define HSH_OFF 135168       // 1024   packed h slice ushort[16 row][32 hu]
#define XSH_OFF 136192       // 64     int[16] tokens
#define SMEM_TOTAL 136256

#define HXBUF 131072         // ushorts per hX buffer (256 blocks * 512); 3 bufs

typedef __bf16 bf16x8 __attribute__((ext_vector_type(8)));
typedef float f32x4 __attribute__((ext_vector_type(4)));
typedef unsigned long long ull;

#define NANP 0xFFFFFFFFu                  // dword of two bf16 NaNs (0xFFFF)
#define NAN8 0xFFFFFFFFFFFFFFFFull

// Coherent (device-scope, L1/L2-bypass) 16-B load.
// NOTE: inline-asm loads are NOT waitcnt-tracked by the compiler; every use
// of the result must be preceded by an explicit s_waitcnt vmcnt (rule #18
// analog — this was R8's bug).
__device__ __forceinline__ uint4 cload16(const unsigned short* p) {
  uint4 r;
  asm volatile("global_load_dwordx4 %0, %1, off sc0 sc1"
               : "=v"(r) : "v"(p) : "memory");
  return r;
}
// Coherent 8-B store via compiler atomics (proven protocol; 8B-atomic).
__device__ __forceinline__ void cstore8(unsigned short* p, ull v) {
  __hip_atomic_store((ull*)p, v, __ATOMIC_RELAXED, __HIP_MEMORY_SCOPE_AGENT);
}

__device__ __forceinline__ unsigned short f2bf(float f) {
  unsigned u = __float_as_uint(f);
  u += 0x7fffu + ((u >> 16) & 1u);   // round-to-nearest-even
  return (unsigned short)(u >> 16);
}
__device__ __forceinline__ float sigf(float x) { return 1.0f / (1.0f + __expf(-x)); }
__device__ __forceinline__ float tanhfast(float x) { return 1.0f - 2.0f / (1.0f + __expf(2.0f * x)); }

// ---- fused prep: tokproj (bid<2048) | WhT (bid<6144) | xpose (bid<6400) ----
__global__ void __launch_bounds__(256)
prep_kernel(const float* __restrict__ emb,
            const float* __restrict__ Wgx, const float* __restrict__ Wix,
            const float* __restrict__ Wfx, const float* __restrict__ Wox,
            const float* __restrict__ bg, const float* __restrict__ bi,
            const float* __restrict__ bf_, const float* __restrict__ bo,
            const float* __restrict__ Wgh, const float* __restrict__ Wih,
            const float* __restrict__ Wfh, const float* __restrict__ Woh,
            const int* __restrict__ x,
            float* __restrict__ tokproj, unsigned short* __restrict__ WhT,
            int* __restrict__ xT) {
  __shared__ float esh[E_];
  const int bid = blockIdx.x;
  if (bid < 2048) {
    const int v = bid >> 4;
    const int c = (bid & 15) * 256 + threadIdx.x;
    const int gate = c >> 10;
    const int j = c & 1023;
    const float* W = (gate == 0) ? Wgx : (gate == 1) ? Wix : (gate == 2) ? Wfx : Wox;
    const float* bias = (gate == 0) ? bg : (gate == 1) ? bi : (gate == 2) ? bf_ : bo;
    esh[threadIdx.x] = emb[v * E_ + threadIdx.x];
    __syncthreads();
    float acc = bias[j];
#pragma unroll 4
    for (int e = 0; e < E_; ++e) acc += esh[e] * W[e * H_ + j];
    tokproj[v * 4096 + c] = acc;
  } else if (bid < 6144) {
    const int c = bid - 2048;
    const int gate = c >> 10;
    const int j = c & 1023;
    const float* W = (gate == 0) ? Wgh : (gate == 1) ? Wih : (gate == 2) ? Wfh : Woh;
    for (int k = threadIdx.x; k < H_; k += 256)
      WhT[c * H_ + k] = f2bf(W[k * H_ + j]);
  } else {
    const int id = (bid - 6144) * 256 + threadIdx.x;  // 65536
    const int s = id >> 7, b = id & 127;
    xT[s * 128 + b] = x[b * S_ + s];
  }
}

// ---- persistent scan: 256 blocks x 512 thr (1 per CU) ----
// POLL-ON-DATA protocol (flagless, 3-buffer rotation):
//   h slices are validity-tagged by construction: h is provably finite/non-NaN,
//   so dword 0xFFFFFFFF (two bf16 NaNs) marks "not yet written". Consumers
//   poll the data chunks directly -> discovery and data arrival are ONE LLC
//   round-trip (was: drain->flag store->flag poll RT->data RT).
//   Rotation: iter s reads buf s%3; publish phase writes NaN-reset into
//   buf (s+2)%3 (dead h^{s-1}), vmcnt(0) drain, then h^{s+1} into buf (s+1)%3.
//   Ordering proof (per-wave): a wave's observation of producer Q's h^{s+1}
//   implies Q's reset of buf (s+2)%3 is LLC-visible (Q drained between reset
//   and data stores) -> its later poll of buf (s+2)%3 sees NaN-or-newer, never
//   stale h^{s-1}. Reset-clobber safety: Q's own iter-s poll succeeding
//   certifies all rg peers (consumers-of-Q = producers-of-Q) finished their
//   iter-(s-1) loads of that buffer.
//   Init: host memset 0xFF (all-NaN) over all 3 bufs; wave0 zero-publishes
//   its buf-0 slice as h^0 (fire-and-forget; memset is stream-ordered).
__global__ void __launch_bounds__(512, 1)
lstm_scan(const int* __restrict__ xT, const float* __restrict__ tokproj,
          const unsigned short* __restrict__ WhT,
          unsigned short* __restrict__ hX, float* __restrict__ hfin) {
  extern __shared__ char smem[];
  float* Zsh = (float*)(smem + ZSH_OFF);
  float* tsh = (float*)(smem + TSH_OFF);
  unsigned short* hsh = (unsigned short*)(smem + HSH_OFF);
  int* xsh = (int*)(smem + XSH_OFF);

  const int bid = blockIdx.x;
  const int rg = bid >> 5;
  const int cg = bid & 31;
  const int tid = threadIdx.x;
  const int w = tid >> 6;          // k-slice owner: k in [w*128, +128)
  const int lane = tid & 63;
  const int l15 = lane & 15;
  const int lq = lane >> 4;

  // ---- one-time: tokproj slice -> LDS as [v][hu][gate] ----
  for (int it = tid; it < 16384; it += 512) {
    const int v = it >> 7, j = it & 127;
    const int gate = j >> 5, hu = j & 31;
    tsh[(v * 33 + hu) * 4 + gate] = tokproj[v * 4096 + gate * 1024 + cg * 32 + hu];
  }
  // ---- one-time: B fragments -> registers ----
  uint4 breg[32];
#pragma unroll
  for (int kc = 0; kc < 4; ++kc) {
#pragma unroll
    for (int t = 0; t < 8; ++t) {
      const int j = t * 16 + l15;
      const int c = ((j >> 5) << 10) + cg * 32 + (j & 31);
      breg[kc * 8 + t] =
          *(const uint4*)(WhT + c * 1024 + (w * 4 + kc) * 32 + lq * 8);
    }
  }

  const int row_own = tid >> 5;      // 0..15
  const int hu = tid & 31;           // 0..31
  const int brow = rg * 16 + row_own;
  const int colg = cg * 32 + hu;

  // fragment bases: producer w*4+kc's slice, this lane's 16B chunk (= lane)
  const unsigned short* abase[4];
#pragma unroll
  for (int kc = 0; kc < 4; ++kc)
    abase[kc] = hX + (rg * 32 + w * 4 + kc) * 512 + lane * 8;

  float creg = 0.f;
  // init: zero-publish own h^0 slice into buf 0 (data; zeros are valid).
  // Host memset(0xFF) already NaN-tagged all 3 buffers (stream-ordered).
  if (tid < 64) {
    unsigned short* dst = hX + bid * 512 + tid * 8;
    cstore8(dst, 0ull);
    cstore8(dst + 4, 0ull);
  }

  int bcur = 0;                       // s%3 ; bnxt=(s+1)%3 ; brst=(s+2)%3
  int bnxt = 1;
  int brst = 2;

  for (int s = 0; s < S_; ++s) {
    int xv = 0;
    if (tid < 16) xv = xT[s * 128 + rg * 16 + tid];

    // ---- poll-on-data: load 4 producer chunks from buf bcur, retry NaN ----
    const int soff = bcur * HXBUF;
    uint4 a[4];
    {
      int need0 = 1, need1 = 1, need2 = 1, need3 = 1;
      int guard = 0;
      for (;;) {
        if (need0) a[0] = cload16(abase[0] + soff);
        if (need1) a[1] = cload16(abase[1] + soff);
        if (need2) a[2] = cload16(abase[2] + soff);
        if (need3) a[3] = cload16(abase[3] + soff);
        // REQUIRED: asm loads are not compiler-waitcnt-tracked (R8 bug)
        asm volatile("s_waitcnt vmcnt(0)" ::: "memory");
        if (need0) need0 = !__all((int)((a[0].x != NANP) & (a[0].z != NANP)));
        if (need1) need1 = !__all((int)((a[1].x != NANP) & (a[1].z != NANP)));
        if (need2) need2 = !__all((int)((a[2].x != NANP) & (a[2].z != NANP)));
        if (need3) need3 = !__all((int)((a[3].x != NANP) & (a[3].z != NANP)));
        if (!(need0 | need1 | need2 | need3)) break;
        if (++guard > (1 << 14)) break;   // hang-breaker: finite wrong answer
        __builtin_amdgcn_s_sleep(1);
      }
    }
    __builtin_amdgcn_sched_barrier(0);
    // per-component keep-alive AFTER the poll so MFMAs can't be hoisted (rule 18)
#pragma unroll
    for (int kc = 0; kc < 4; ++kc) {
      asm volatile("" : "+v"(a[kc].x), "+v"(a[kc].y), "+v"(a[kc].z), "+v"(a[kc].w));
    }

    if (tid < 16) xsh[tid] = xv;

    // ---- MFMA: wave covers k [w*128,+128) x all 128 cols ----
    f32x4 acc[8];
#pragma unroll
    for (int t = 0; t < 8; ++t) acc[t] = (f32x4){0.f, 0.f, 0.f, 0.f};
#pragma unroll
    for (int kc = 0; kc < 4; ++kc) {
      const bf16x8 av = __builtin_bit_cast(bf16x8, a[kc]);
#pragma unroll
      for (int t = 0; t < 8; ++t)
        acc[t] = __builtin_amdgcn_mfma_f32_16x16x32_bf16(
            av, __builtin_bit_cast(bf16x8, breg[kc * 8 + t]), acc[t], 0, 0, 0);
    }
    // epilogue: pack per-row gate quads -> 2 b128 writes per r_
#pragma unroll
    for (int r_ = 0; r_ < 4; ++r_) {
      const int row = w * 16 + lq * 4 + r_;
      f32x4 lo = {acc[0][r_], acc[2][r_], acc[4][r_], acc[6][r_]};
      f32x4 hi = {acc[1][r_], acc[3][r_], acc[5][r_], acc[7][r_]};
      *(f32x4*)(Zsh + (row * 33 + l15) * 4) = lo;
      *(f32x4*)(Zsh + (row * 33 + l15 + 16) * 4) = hi;
    }
    __syncthreads();   // F

    // ---- gate pass: thread owns (row_own, hu); all-b128 LDS ----
    {
      const int xb = xsh[row_own];
      f32x4 z4 = *(const f32x4*)(tsh + (xb * 33 + hu) * 4);
#pragma unroll
      for (int w8 = 0; w8 < 8; ++w8)
        z4 += *(const f32x4*)(Zsh + ((w8 * 16 + row_own) * 33 + hu) * 4);
      const float gv = tanhfast(z4[0]);
      const float iv = sigf(z4[1]);
      const float fv = sigf(z4[2]);
      const float ov = sigf(z4[3]);
      creg = gv * iv + creg * fv;
      const float hv = tanhfast(creg) * ov;
      hsh[row_own * 32 + hu] = f2bf(hv);
      if (s == S_ - 1) hfin[brow * H_ + colg] = hv;
    }
    __syncthreads();   // H

    // ---- publish (wave 0): reset brst -> drain -> data into bnxt ----
    // chunk tid <- hsh[row=tid&15][hu-chunk=tid>>4] (16B contiguous in hsh)
    if (tid < 64) {
      unsigned short* rdst = hX + brst * HXBUF + bid * 512 + tid * 8;
      cstore8(rdst, NAN8);
      cstore8(rdst + 4, NAN8);
      asm volatile("s_waitcnt vmcnt(0)" ::: "memory");   // reset globally visible
      const ull* hp = (const ull*)hsh;
      const int si = (tid & 15) * 8 + (tid >> 4) * 2;
      unsigned short* dst = hX + bnxt * HXBUF + bid * 512 + tid * 8;
      cstore8(dst, hp[si]);
      cstore8(dst + 4, hp[si + 1]);
      // no drain, no flag: consumers poll the data itself
    }
    // rotate buffers
    const int t_ = bcur; bcur = bnxt; bnxt = brst; brst = t_;
    // no trailing barrier: barrier F of step s+1 protects Zsh/xsh; poll-success
    // transitively certifies peers' reads before buffer reuse (see header).
  }
}

// ---- p = hfin @ W_ph + b_p ; out = log_softmax(p) ----
__global__ void __launch_bounds__(256)
classify_kernel(const float* __restrict__ hfin, const float* __restrict__ Wph,
                const float* __restrict__ bp, float* __restrict__ out) {
  __shared__ float red[256 * 10];
  const int b = blockIdx.x, tid = threadIdx.x;
  float acc[10];
#pragma unroll
  for (int c = 0; c < 10; ++c) acc[c] = 0.f;
  for (int k = tid; k < H_; k += 256) {
    const float hv = hfin[b * H_ + k];
    const float* w = Wph + k * 10;
#pragma unroll
    for (int c = 0; c < 10; ++c) acc[c] += hv * w[c];
  }
#pragma unroll
  for (int c = 0; c < 10; ++c) red[tid * 10 + c] = acc[c];
  __syncthreads();
  for (int off = 128; off >= 1; off >>= 1) {
    if (tid < off) {
#pragma unroll
      for (int c = 0; c < 10; ++c) red[tid * 10 + c] += red[(tid + off) * 10 + c];
    }
    __syncthreads();
  }
  if (tid == 0) {
    float p[10];
    float m = -1e30f;
#pragma unroll
    for (int c = 0; c < 10; ++c) { p[c] = red[c] + bp[c]; m = fmaxf(m, p[c]); }
    float ssum = 0.f;
#pragma unroll
    for (int c = 0; c < 10; ++c) ssum += __expf(p[c] - m);
    const float lse = m + __logf(ssum);
#pragma unroll
    for (int c = 0; c < 10; ++c) out[b * 10 + c] = p[c] - lse;
  }
}

extern "C" void kernel_launch(void* const* d_in, const int* in_sizes, int n_in,
                              void* d_out, int out_size, void* d_ws, size_t ws_size,
                              hipStream_t stream) {
  (void)in_sizes; (void)n_in; (void)out_size; (void)ws_size;
  const int* x = (const int*)d_in[0];
  const float* emb = (const float*)d_in[1];
  const float* Wgx = (const float*)d_in[2];
  const float* Wgh = (const float*)d_in[3];
  const float* bg = (const float*)d_in[4];
  const float* Wix = (const float*)d_in[5];
  const float* Wih = (const float*)d_in[6];
  const float* bi = (const float*)d_in[7];
  const float* Wfx = (const float*)d_in[8];
  const float* Wfh = (const float*)d_in[9];
  const float* bf_ = (const float*)d_in[10];
  const float* Wox = (const float*)d_in[11];
  const float* Woh = (const float*)d_in[12];
  const float* bo = (const float*)d_in[13];
  const float* Wph = (const float*)d_in[14];
  const float* bp = (const float*)d_in[15];
  float* out = (float*)d_out;

  char* ws = (char*)d_ws;
  float* tokproj = (float*)ws;                                  // 2 MB
  unsigned short* WhT = (unsigned short*)(ws + 2097152);        // 8 MB
  unsigned short* hX = (unsigned short*)(ws + 10485760);        // 768 KB (3 bufs)
  float* hfin = (float*)(ws + 11272192);                        // 512 KB
  int* xT = (int*)(ws + 11796480);                              // 256 KB

  // NaN-tag all 3 h buffers (0xFF bytes -> every bf16 = 0xFFFF = NaN)
  (void)hipMemsetAsync(hX, 0xFF, 786432, stream);
  (void)hipFuncSetAttribute(reinterpret_cast<const void*>(lstm_scan),
                            hipFuncAttributeMaxDynamicSharedMemorySize, SMEM_TOTAL);

  prep_kernel<<<dim3(6400), dim3(256), 0, stream>>>(
      emb, Wgx, Wix, Wfx, Wox, bg, bi, bf_, bo,
      Wgh, Wih, Wfh, Woh, x, tokproj, WhT, xT);
  lstm_scan<<<dim3(256), dim3(512), SMEM_TOTAL, stream>>>(
      xT, tokproj, WhT, hX, hfin);
  classify_kernel<<<dim3(128), dim3(256), 0, stream>>>(hfin, Wph, bp, out);
}

// Round 10
// 1851.993 us; speedup vs baseline: 1.0411x; 1.0411x over previous
//
#include <hip/hip_runtime.h>

#define H_ 1024
#define B_ 128
#define S_ 512
#define V_ 128
#define E_ 256

// LDS layout (bytes)
// Zsh: [8 w8][16 row][33 hu-slots][4 gates] f32  (pad 33 breaks bank aliasing)
// tsh: [128 v][33 hu-slots][4 gates] f32
#define ZSH_OFF 0            // 67584
#define TSH_OFF 67584        // 67584
#define HSH_OFF 135168       // 1024   packed h slice ushort[16 row][32 hu]
#define XSH_OFF 136192       // 64     int[16] tokens
#define SMEM_TOTAL 136256

#define HXBUF 131072         // ushorts per hX buffer (256 blocks * 512); 3 bufs

typedef __bf16 bf16x8 __attribute__((ext_vector_type(8)));
typedef float f32x4 __attribute__((ext_vector_type(4)));
typedef unsigned long long ull;

#define NANP 0xFFFFFFFFu                  // dword of two bf16 NaNs (0xFFFF)
#define NAN8 0xFFFFFFFFFFFFFFFFull

// Coherent (device-scope, L1/L2-bypass) 16-B load.
// NOTE: inline-asm loads are NOT waitcnt-tracked by the compiler; every use
// of the result must be preceded by an explicit s_waitcnt vmcnt (R8 lesson).
__device__ __forceinline__ uint4 cload16(const unsigned short* p) {
  uint4 r;
  asm volatile("global_load_dwordx4 %0, %1, off sc0 sc1"
               : "=v"(r) : "v"(p) : "memory");
  return r;
}
// Coherent 8-B store via compiler atomics (proven protocol; 8B-atomic).
__device__ __forceinline__ void cstore8(unsigned short* p, ull v) {
  __hip_atomic_store((ull*)p, v, __ATOMIC_RELAXED, __HIP_MEMORY_SCOPE_AGENT);
}

__device__ __forceinline__ unsigned short f2bf(float f) {
  unsigned u = __float_as_uint(f);
  u += 0x7fffu + ((u >> 16) & 1u);   // round-to-nearest-even
  return (unsigned short)(u >> 16);
}
__device__ __forceinline__ float sigf(float x) { return 1.0f / (1.0f + __expf(-x)); }
__device__ __forceinline__ float tanhfast(float x) { return 1.0f - 2.0f / (1.0f + __expf(2.0f * x)); }

// ---- fused prep: tokproj (bid<2048) | WhT (bid<6144) | xpose (bid<6400) ----
__global__ void __launch_bounds__(256)
prep_kernel(const float* __restrict__ emb,
            const float* __restrict__ Wgx, const float* __restrict__ Wix,
            const float* __restrict__ Wfx, const float* __restrict__ Wox,
            const float* __restrict__ bg, const float* __restrict__ bi,
            const float* __restrict__ bf_, const float* __restrict__ bo,
            const float* __restrict__ Wgh, const float* __restrict__ Wih,
            const float* __restrict__ Wfh, const float* __restrict__ Woh,
            const int* __restrict__ x,
            float* __restrict__ tokproj, unsigned short* __restrict__ WhT,
            int* __restrict__ xT) {
  __shared__ float esh[E_];
  const int bid = blockIdx.x;
  if (bid < 2048) {
    const int v = bid >> 4;
    const int c = (bid & 15) * 256 + threadIdx.x;
    const int gate = c >> 10;
    const int j = c & 1023;
    const float* W = (gate == 0) ? Wgx : (gate == 1) ? Wix : (gate == 2) ? Wfx : Wox;
    const float* bias = (gate == 0) ? bg : (gate == 1) ? bi : (gate == 2) ? bf_ : bo;
    esh[threadIdx.x] = emb[v * E_ + threadIdx.x];
    __syncthreads();
    float acc = bias[j];
#pragma unroll 4
    for (int e = 0; e < E_; ++e) acc += esh[e] * W[e * H_ + j];
    tokproj[v * 4096 + c] = acc;
  } else if (bid < 6144) {
    const int c = bid - 2048;
    const int gate = c >> 10;
    const int j = c & 1023;
    const float* W = (gate == 0) ? Wgh : (gate == 1) ? Wih : (gate == 2) ? Wfh : Woh;
    for (int k = threadIdx.x; k < H_; k += 256)
      WhT[c * H_ + k] = f2bf(W[k * H_ + j]);
  } else {
    const int id = (bid - 6144) * 256 + threadIdx.x;  // 65536
    const int s = id >> 7, b = id & 127;
    xT[s * 128 + b] = x[b * S_ + s];
  }
}

// ---- persistent scan: 256 blocks x 512 thr (1 per CU) ----
// POLL-ON-DATA protocol (flagless, 3-buffer rotation) — HW-proven in R9.
// R10 change: the NaN-reset of slot (s+2)%3 is issued EARLY (right after
// barrier F, fire-and-forget) instead of inside the publish phase; its LLC
// flight hides under the gate phase + barrier H. The publish-time vmcnt(0)
// (needed anyway before data stores) then certifies "reset in LLC before
// h^{s+1} data issued" at near-zero residual cost — R9 paid a full serialized
// reset+drain RT here, which cancelled the RT it saved over the flag protocol.
//   Certification to START the reset (all readers of h^{s-1} done): barrier F
//   means all 8 waves' polls saw h^s from all 32 rg producers => every rg
//   block completed iter s-1 => finished reading h^{s-1} (slot's old content).
//   Stale-read proof (consumer): wave observes Q's h^{s+1} at iter s+1; Q
//   issued h^{s+1} data only after vmcnt(0) covering its reset => reset in
//   LLC => wave's first poll of that slot (iter s+2) sees NaN-or-h^{s+2}.
//   Init: host memset 0xFF (all-NaN) over all 3 bufs; wave0 zero-publishes
//   its buf-0 slice as h^0 (fire-and-forget; memset is stream-ordered).
__global__ void __launch_bounds__(512, 1)
lstm_scan(const int* __restrict__ xT, const float* __restrict__ tokproj,
          const unsigned short* __restrict__ WhT,
          unsigned short* __restrict__ hX, float* __restrict__ hfin) {
  extern __shared__ char smem[];
  float* Zsh = (float*)(smem + ZSH_OFF);
  float* tsh = (float*)(smem + TSH_OFF);
  unsigned short* hsh = (unsigned short*)(smem + HSH_OFF);
  int* xsh = (int*)(smem + XSH_OFF);

  const int bid = blockIdx.x;
  const int rg = bid >> 5;
  const int cg = bid & 31;
  const int tid = threadIdx.x;
  const int w = tid >> 6;          // k-slice owner: k in [w*128, +128)
  const int lane = tid & 63;
  const int l15 = lane & 15;
  const int lq = lane >> 4;

  // ---- one-time: tokproj slice -> LDS as [v][hu][gate] ----
  for (int it = tid; it < 16384; it += 512) {
    const int v = it >> 7, j = it & 127;
    const int gate = j >> 5, hu = j & 31;
    tsh[(v * 33 + hu) * 4 + gate] = tokproj[v * 4096 + gate * 1024 + cg * 32 + hu];
  }
  // ---- one-time: B fragments -> registers ----
  uint4 breg[32];
#pragma unroll
  for (int kc = 0; kc < 4; ++kc) {
#pragma unroll
    for (int t = 0; t < 8; ++t) {
      const int j = t * 16 + l15;
      const int c = ((j >> 5) << 10) + cg * 32 + (j & 31);
      breg[kc * 8 + t] =
          *(const uint4*)(WhT + c * 1024 + (w * 4 + kc) * 32 + lq * 8);
    }
  }

  const int row_own = tid >> 5;      // 0..15
  const int hu = tid & 31;           // 0..31
  const int brow = rg * 16 + row_own;
  const int colg = cg * 32 + hu;

  // fragment bases: producer w*4+kc's slice, this lane's 16B chunk (= lane)
  const unsigned short* abase[4];
#pragma unroll
  for (int kc = 0; kc < 4; ++kc)
    abase[kc] = hX + (rg * 32 + w * 4 + kc) * 512 + lane * 8;

  float creg = 0.f;
  // init: zero-publish own h^0 slice into buf 0 (data; zeros are valid).
  // Host memset(0xFF) already NaN-tagged all 3 buffers (stream-ordered).
  if (tid < 64) {
    unsigned short* dst = hX + bid * 512 + tid * 8;
    cstore8(dst, 0ull);
    cstore8(dst + 4, 0ull);
  }

  int bcur = 0;                       // s%3 ; bnxt=(s+1)%3 ; brst=(s+2)%3
  int bnxt = 1;
  int brst = 2;

  for (int s = 0; s < S_; ++s) {
    int xv = 0;
    if (tid < 16) xv = xT[s * 128 + rg * 16 + tid];

    // ---- poll-on-data: load 4 producer chunks from buf bcur, retry NaN ----
    const int soff = bcur * HXBUF;
    uint4 a[4];
    {
      int need0 = 1, need1 = 1, need2 = 1, need3 = 1;
      int guard = 0;
      for (;;) {
        if (need0) a[0] = cload16(abase[0] + soff);
        if (need1) a[1] = cload16(abase[1] + soff);
        if (need2) a[2] = cload16(abase[2] + soff);
        if (need3) a[3] = cload16(abase[3] + soff);
        // REQUIRED: asm loads are not compiler-waitcnt-tracked (R8 bug)
        asm volatile("s_waitcnt vmcnt(0)" ::: "memory");
        if (need0) need0 = !__all((int)((a[0].x != NANP) & (a[0].z != NANP)));
        if (need1) need1 = !__all((int)((a[1].x != NANP) & (a[1].z != NANP)));
        if (need2) need2 = !__all((int)((a[2].x != NANP) & (a[2].z != NANP)));
        if (need3) need3 = !__all((int)((a[3].x != NANP) & (a[3].z != NANP)));
        if (!(need0 | need1 | need2 | need3)) break;
        if (++guard > (1 << 14)) break;   // hang-breaker: finite wrong answer
        __builtin_amdgcn_s_sleep(1);
      }
    }
    __builtin_amdgcn_sched_barrier(0);
    // per-component keep-alive AFTER the poll so MFMAs can't be hoisted (rule 18)
#pragma unroll
    for (int kc = 0; kc < 4; ++kc) {
      asm volatile("" : "+v"(a[kc].x), "+v"(a[kc].y), "+v"(a[kc].z), "+v"(a[kc].w));
    }

    if (tid < 16) xsh[tid] = xv;

    // ---- MFMA: wave covers k [w*128,+128) x all 128 cols ----
    f32x4 acc[8];
#pragma unroll
    for (int t = 0; t < 8; ++t) acc[t] = (f32x4){0.f, 0.f, 0.f, 0.f};
#pragma unroll
    for (int kc = 0; kc < 4; ++kc) {
      const bf16x8 av = __builtin_bit_cast(bf16x8, a[kc]);
#pragma unroll
      for (int t = 0; t < 8; ++t)
        acc[t] = __builtin_amdgcn_mfma_f32_16x16x32_bf16(
            av, __builtin_bit_cast(bf16x8, breg[kc * 8 + t]), acc[t], 0, 0, 0);
    }
    // epilogue: pack per-row gate quads -> 2 b128 writes per r_
#pragma unroll
    for (int r_ = 0; r_ < 4; ++r_) {
      const int row = w * 16 + lq * 4 + r_;
      f32x4 lo = {acc[0][r_], acc[2][r_], acc[4][r_], acc[6][r_]};
      f32x4 hi = {acc[1][r_], acc[3][r_], acc[5][r_], acc[7][r_]};
      *(f32x4*)(Zsh + (row * 33 + l15) * 4) = lo;
      *(f32x4*)(Zsh + (row * 33 + l15 + 16) * 4) = hi;
    }
    __syncthreads();   // F  (certification point: all waves' polls succeeded)

    // ---- EARLY NaN-reset of slot brst (wave 0, fire-and-forget) ----
    // Flight hides under gate + barrier H; publish vmcnt(0) certifies landing.
    if (tid < 64) {
      unsigned short* rdst = hX + brst * HXBUF + bid * 512 + tid * 8;
      cstore8(rdst, NAN8);
      cstore8(rdst + 4, NAN8);
    }

    // ---- gate pass: thread owns (row_own, hu); all-b128 LDS ----
    {
      const int xb = xsh[row_own];
      f32x4 z4 = *(const f32x4*)(tsh + (xb * 33 + hu) * 4);
#pragma unroll
      for (int w8 = 0; w8 < 8; ++w8)
        z4 += *(const f32x4*)(Zsh + ((w8 * 16 + row_own) * 33 + hu) * 4);
      const float gv = tanhfast(z4[0]);
      const float iv = sigf(z4[1]);
      const float fv = sigf(z4[2]);
      const float ov = sigf(z4[3]);
      creg = gv * iv + creg * fv;
      const float hv = tanhfast(creg) * ov;
      hsh[row_own * 32 + hu] = f2bf(hv);
      if (s == S_ - 1) hfin[brow * H_ + colg] = hv;
    }
    __syncthreads();   // H

    // ---- publish (wave 0): vmcnt(0) [reset landed] -> data into bnxt ----
    // chunk tid <- hsh[row=tid&15][hu-chunk=tid>>4] (16B contiguous in hsh)
    if (tid < 64) {
      asm volatile("s_waitcnt vmcnt(0)" ::: "memory");   // reset in LLC, cheap now
      const ull* hp = (const ull*)hsh;
      const int si = (tid & 15) * 8 + (tid >> 4) * 2;
      unsigned short* dst = hX + bnxt * HXBUF + bid * 512 + tid * 8;
      cstore8(dst, hp[si]);
      cstore8(dst + 4, hp[si + 1]);
      // no drain, no flag: consumers poll the data itself
    }
    // rotate buffers
    const int t_ = bcur; bcur = bnxt; bnxt = brst; brst = t_;
    // no trailing barrier: barrier F of step s+1 protects Zsh/xsh; poll-success
    // transitively certifies peers' reads before buffer reuse (see header).
  }
}

// ---- p = hfin @ W_ph + b_p ; out = log_softmax(p) ----
__global__ void __launch_bounds__(256)
classify_kernel(const float* __restrict__ hfin, const float* __restrict__ Wph,
                const float* __restrict__ bp, float* __restrict__ out) {
  __shared__ float red[256 * 10];
  const int b = blockIdx.x, tid = threadIdx.x;
  float acc[10];
#pragma unroll
  for (int c = 0; c < 10; ++c) acc[c] = 0.f;
  for (int k = tid; k < H_; k += 256) {
    const float hv = hfin[b * H_ + k];
    const float* w = Wph + k * 10;
#pragma unroll
    for (int c = 0; c < 10; ++c) acc[c] += hv * w[c];
  }
#pragma unroll
  for (int c = 0; c < 10; ++c) red[tid * 10 + c] = acc[c];
  __syncthreads();
  for (int off = 128; off >= 1; off >>= 1) {
    if (tid < off) {
#pragma unroll
      for (int c = 0; c < 10; ++c) red[tid * 10 + c] += red[(tid + off) * 10 + c];
    }
    __syncthreads();
  }
  if (tid == 0) {
    float p[10];
    float m = -1e30f;
#pragma unroll
    for (int c = 0; c < 10; ++c) { p[c] = red[c] + bp[c]; m = fmaxf(m, p[c]); }
    float ssum = 0.f;
#pragma unroll
    for (int c = 0; c < 10; ++c) ssum += __expf(p[c] - m);
    const float lse = m + __logf(ssum);
#pragma unroll
    for (int c = 0; c < 10; ++c) out[b * 10 + c] = p[c] - lse;
  }
}

extern "C" void kernel_launch(void* const* d_in, const int* in_sizes, int n_in,
                              void* d_out, int out_size, void* d_ws, size_t ws_size,
                              hipStream_t stream) {
  (void)in_sizes; (void)n_in; (void)out_size; (void)ws_size;
  const int* x = (const int*)d_in[0];
  const float* emb = (const float*)d_in[1];
  const float* Wgx = (const float*)d_in[2];
  const float* Wgh = (const float*)d_in[3];
  const float* bg = (const float*)d_in[4];
  const float* Wix = (const float*)d_in[5];
  const float* Wih = (const float*)d_in[6];
  const float* bi = (const float*)d_in[7];
  const float* Wfx = (const float*)d_in[8];
  const float* Wfh = (const float*)d_in[9];
  const float* bf_ = (const float*)d_in[10];
  const float* Wox = (const float*)d_in[11];
  const float* Woh = (const float*)d_in[12];
  const float* bo = (const float*)d_in[13];
  const float* Wph = (const float*)d_in[14];
  const float* bp = (const float*)d_in[15];
  float* out = (float*)d_out;

  char* ws = (char*)d_ws;
  float* tokproj = (float*)ws;                                  // 2 MB
  unsigned short* WhT = (unsigned short*)(ws + 2097152);        // 8 MB
  unsigned short* hX = (unsigned short*)(ws + 10485760);        // 768 KB (3 bufs)
  float* hfin = (float*)(ws + 11272192);                        // 512 KB
  int* xT = (int*)(ws + 11796480);                              // 256 KB

  // NaN-tag all 3 h buffers (0xFF bytes -> every bf16 = 0xFFFF = NaN)
  (void)hipMemsetAsync(hX, 0xFF, 786432, stream);
  (void)hipFuncSetAttribute(reinterpret_cast<const void*>(lstm_scan),
                            hipFuncAttributeMaxDynamicSharedMemorySize, SMEM_TOTAL);

  prep_kernel<<<dim3(6400), dim3(256), 0, stream>>>(
      emb, Wgx, Wix, Wfx, Wox, bg, bi, bf_, bo,
      Wgh, Wih, Wfh, Woh, x, tokproj, WhT, xT);
  lstm_scan<<<dim3(256), dim3(512), SMEM_TOTAL, stream>>>(
      xT, tokproj, WhT, hX, hfin);
  classify_kernel<<<dim3(128), dim3(256), 0, stream>>>(hfin, Wph, bp, out);
}

// Round 11
// 1676.139 us; speedup vs baseline: 1.1504x; 1.1049x over previous
//
#include <hip/hip_runtime.h>

#define H_ 1024
#define B_ 128
#define S_ 512
#define V_ 128
#define E_ 256

// LDS layout (bytes)
// Zsh: [8 w8][16 row][33 hu-slots][4 gates] f32  (pad 33 breaks bank aliasing)
// tsh: [128 v][33 hu-slots][4 gates] f32
#define ZSH_OFF 0            // 67584
#define TSH_OFF 67584        // 67584
#define XSH_OFF 135168       // 64     int[16] tokens
#define SMEM_TOTAL 135232

#define HXBUF 131072         // ushorts per hX buffer (256 blocks * 512); 2 bufs

typedef __bf16 bf16x8 __attribute__((ext_vector_type(8)));
typedef float f32x4 __attribute__((ext_vector_type(4)));
typedef unsigned long long ull;

// Coherent (device-scope, L1/L2-bypass) 16-B load.
// NOTE: inline-asm loads are NOT waitcnt-tracked by the compiler; every use
// of the result must be preceded by an explicit s_waitcnt vmcnt (R8 lesson).
__device__ __forceinline__ uint4 cload16(const unsigned short* p) {
  uint4 r;
  asm volatile("global_load_dwordx4 %0, %1, off sc0 sc1"
               : "=v"(r) : "v"(p) : "memory");
  return r;
}
// Coherent 8-B store via compiler atomics (proven protocol; 8B-atomic).
__device__ __forceinline__ void cstore8(unsigned short* p, ull v) {
  __hip_atomic_store((ull*)p, v, __ATOMIC_RELAXED, __HIP_MEMORY_SCOPE_AGENT);
}

__device__ __forceinline__ unsigned short f2bf(float f) {
  unsigned u = __float_as_uint(f);
  u += 0x7fffu + ((u >> 16) & 1u);   // round-to-nearest-even
  return (unsigned short)(u >> 16);
}
__device__ __forceinline__ float sigf(float x) { return 1.0f / (1.0f + __expf(-x)); }
__device__ __forceinline__ float tanhfast(float x) { return 1.0f - 2.0f / (1.0f + __expf(2.0f * x)); }

// ---- fused prep: tokproj (bid<2048) | WhT (bid<6144) | xpose (bid<6400) ----
__global__ void __launch_bounds__(256)
prep_kernel(const float* __restrict__ emb,
            const float* __restrict__ Wgx, const float* __restrict__ Wix,
            const float* __restrict__ Wfx, const float* __restrict__ Wox,
            const float* __restrict__ bg, const float* __restrict__ bi,
            const float* __restrict__ bf_, const float* __restrict__ bo,
            const float* __restrict__ Wgh, const float* __restrict__ Wih,
            const float* __restrict__ Wfh, const float* __restrict__ Woh,
            const int* __restrict__ x,
            float* __restrict__ tokproj, unsigned short* __restrict__ WhT,
            int* __restrict__ xT) {
  __shared__ float esh[E_];
  const int bid = blockIdx.x;
  if (bid < 2048) {
    const int v = bid >> 4;
    const int c = (bid & 15) * 256 + threadIdx.x;
    const int gate = c >> 10;
    const int j = c & 1023;
    const float* W = (gate == 0) ? Wgx : (gate == 1) ? Wix : (gate == 2) ? Wfx : Wox;
    const float* bias = (gate == 0) ? bg : (gate == 1) ? bi : (gate == 2) ? bf_ : bo;
    esh[threadIdx.x] = emb[v * E_ + threadIdx.x];
    __syncthreads();
    float acc = bias[j];
#pragma unroll 4
    for (int e = 0; e < E_; ++e) acc += esh[e] * W[e * H_ + j];
    tokproj[v * 4096 + c] = acc;
  } else if (bid < 6144) {
    const int c = bid - 2048;
    const int gate = c >> 10;
    const int j = c & 1023;
    const float* W = (gate == 0) ? Wgh : (gate == 1) ? Wih : (gate == 2) ? Wfh : Woh;
    for (int k = threadIdx.x; k < H_; k += 256)
      WhT[c * H_ + k] = f2bf(W[k * H_ + j]);
  } else {
    const int id = (bid - 6144) * 256 + threadIdx.x;  // 65536
    const int s = id >> 7, b = id & 127;
    xT[s * 128 + b] = x[b * S_ + s];
  }
}

// ---- persistent scan: 256 blocks x 512 thr (1 per CU) ----
// bid: rg = bid>>5 owns batch rows [rg*16,+16); cg = bid&31 owns hidden units
// [cg*32,+32)  (baseline mapping, proven). Flag protocol (R7-proven, 2 bufs).
// h slice (1 KB) published FRAGMENT-MAJOR: 16B chunk c = h[row=c&15][hu 8-chunk
// c>>4]; a wave's MFMA A-fragment is a unit-stride 64x16B load (chunk = lane).
// R11 change (publish tail): hsh LDS round-trip removed. Each thread packs its
// h value into 8B chunks IN-REGISTER (2x shfl_xor rounds); lanes l%4==0 of
// EVERY wave store their own 2 rows and drain BEFORE barrier H; wave0 then
// stores only the flag. Stores start as each wave finishes gates (skew
// overlapped), drains run in parallel -> flag lands at barrier exit.
__global__ void __launch_bounds__(512, 1)
lstm_scan(const int* __restrict__ xT, const float* __restrict__ tokproj,
          const unsigned short* __restrict__ WhT,
          unsigned short* __restrict__ hX, float* __restrict__ hfin,
          unsigned* __restrict__ pub) {
  extern __shared__ char smem[];
  float* Zsh = (float*)(smem + ZSH_OFF);
  float* tsh = (float*)(smem + TSH_OFF);
  int* xsh = (int*)(smem + XSH_OFF);

  const int bid = blockIdx.x;
  const int rg = bid >> 5;
  const int cg = bid & 31;
  const int tid = threadIdx.x;
  const int w = tid >> 6;          // k-slice owner: k in [w*128, +128)
  const int lane = tid & 63;
  const int l15 = lane & 15;
  const int lq = lane >> 4;

  // ---- one-time: tokproj slice -> LDS as [v][hu][gate] ----
  for (int it = tid; it < 16384; it += 512) {
    const int v = it >> 7, j = it & 127;
    const int gate = j >> 5, hu = j & 31;
    tsh[(v * 33 + hu) * 4 + gate] = tokproj[v * 4096 + gate * 1024 + cg * 32 + hu];
  }
  // ---- one-time: B fragments -> registers ----
  uint4 breg[32];
#pragma unroll
  for (int kc = 0; kc < 4; ++kc) {
#pragma unroll
    for (int t = 0; t < 8; ++t) {
      const int j = t * 16 + l15;
      const int c = ((j >> 5) << 10) + cg * 32 + (j & 31);
      breg[kc * 8 + t] =
          *(const uint4*)(WhT + c * 1024 + (w * 4 + kc) * 32 + lq * 8);
    }
  }

  const int row_own = tid >> 5;      // 0..15
  const int hu = tid & 31;           // 0..31
  const int brow = rg * 16 + row_own;
  const int colg = cg * 32 + hu;

  // poll binding: lane polls producer w*4 + (lane&3); the wave reconverges
  // (and issues its loads) only after ALL 4 of its producers are ready.
  const unsigned* myflag = pub + (rg * 32 + w * 4 + (lane & 3)) * 32;
  // fragment bases: producer w*4+kc's slice, this lane's 16B chunk (= lane)
  const unsigned short* abase[4];
#pragma unroll
  for (int kc = 0; kc < 4; ++kc)
    abase[kc] = hX + (rg * 32 + w * 4 + kc) * 512 + lane * 8;

  float creg = 0.f;
  // zero own h^0 slice (buffer 0) with packed coherent stores (proven form)
  if (tid < 128) cstore8(hX + bid * 512 + tid * 4, 0ull);
  asm volatile("s_waitcnt vmcnt(0)" ::: "memory");
  __syncthreads();
  if (tid == 0)
    __hip_atomic_store(pub + bid * 32, 1u, __ATOMIC_RELAXED, __HIP_MEMORY_SCOPE_AGENT);

  for (int s = 0; s < S_; ++s) {
    int xv = 0;
    if (tid < 16) xv = xT[s * 128 + rg * 16 + tid];

    const unsigned tgt = (unsigned)(s + 1);
    while (__hip_atomic_load(myflag, __ATOMIC_RELAXED, __HIP_MEMORY_SCOPE_AGENT) < tgt)
      __builtin_amdgcn_s_sleep(1);

    const int soff = (s & 1) * HXBUF;
    uint4 a[4];
#pragma unroll
    for (int kc = 0; kc < 4; ++kc) a[kc] = cload16(abase[kc] + soff);
    asm volatile("s_waitcnt vmcnt(0)" ::: "memory");
    __builtin_amdgcn_sched_barrier(0);
    // per-component keep-alive AFTER the waitcnt so MFMAs can't be hoisted
#pragma unroll
    for (int kc = 0; kc < 4; ++kc) {
      asm volatile("" : "+v"(a[kc].x), "+v"(a[kc].y), "+v"(a[kc].z), "+v"(a[kc].w));
    }

    if (tid < 16) xsh[tid] = xv;

    // ---- MFMA: wave covers k [w*128,+128) x all 128 cols ----
    f32x4 acc[8];
#pragma unroll
    for (int t = 0; t < 8; ++t) acc[t] = (f32x4){0.f, 0.f, 0.f, 0.f};
#pragma unroll
    for (int kc = 0; kc < 4; ++kc) {
      const bf16x8 av = __builtin_bit_cast(bf16x8, a[kc]);
#pragma unroll
      for (int t = 0; t < 8; ++t)
        acc[t] = __builtin_amdgcn_mfma_f32_16x16x32_bf16(
            av, __builtin_bit_cast(bf16x8, breg[kc * 8 + t]), acc[t], 0, 0, 0);
    }
    // epilogue: pack per-row gate quads -> 2 b128 writes per r_
#pragma unroll
    for (int r_ = 0; r_ < 4; ++r_) {
      const int row = w * 16 + lq * 4 + r_;
      f32x4 lo = {acc[0][r_], acc[2][r_], acc[4][r_], acc[6][r_]};
      f32x4 hi = {acc[1][r_], acc[3][r_], acc[5][r_], acc[7][r_]};
      *(f32x4*)(Zsh + (row * 33 + l15) * 4) = lo;
      *(f32x4*)(Zsh + (row * 33 + l15 + 16) * 4) = hi;
    }
    __syncthreads();   // F

    // ---- gate pass + in-register publish pack ----
    {
      const int xb = xsh[row_own];
      f32x4 z4 = *(const f32x4*)(tsh + (xb * 33 + hu) * 4);
#pragma unroll
      for (int w8 = 0; w8 < 8; ++w8)
        z4 += *(const f32x4*)(Zsh + ((w8 * 16 + row_own) * 33 + hu) * 4);
      const float gv = tanhfast(z4[0]);
      const float iv = sigf(z4[1]);
      const float fv = sigf(z4[2]);
      const float ov = sigf(z4[3]);
      creg = gv * iv + creg * fv;
      const float hv = tanhfast(creg) * ov;
      if (s == S_ - 1) hfin[brow * H_ + colg] = hv;

      // pack 4 consecutive hu into 8B: 2 shfl_xor rounds
      // (wave w holds rows {2w, 2w+1}: lanes 0..31 -> row 2w, 32..63 -> 2w+1;
      //  xor distances 1,2 stay within each 32-lane half)
      const unsigned hvu = (unsigned)f2bf(hv);
      const unsigned o1 = (unsigned)__shfl_xor((int)hvu, 1);
      const unsigned p01 = (hvu & 0xFFFFu) | (o1 << 16);     // [hu, hu+1] on even lanes
      const unsigned o2 = (unsigned)__shfl_xor((int)p01, 2);
      const ull q = (ull)p01 | ((ull)o2 << 32);              // [hu..hu+3] on lanes l%4==0

      if ((lane & 3) == 0) {
        const int prow = 2 * w + (lane >> 5);   // == row_own
        const int hu0 = lane & 31;              // == hu
        // fragment-major ushort offset: chunk (prow + (hu0>>3)*16), pos hu0&7
        unsigned short* dst = hX + ((s + 1) & 1) * HXBUF + bid * 512
                              + (prow + ((hu0 >> 3) << 4)) * 8 + (hu0 & 7);
        cstore8(dst, q);
      }
    }
    // per-wave drain BEFORE barrier: all 8 waves' stores LLC-ordered in parallel
    asm volatile("s_waitcnt vmcnt(0)" ::: "memory");
    __syncthreads();   // H
    // flag-only store: certifies all waves' drained stores
    if (tid == 0)
      __hip_atomic_store(pub + bid * 32, (unsigned)(s + 2),
                         __ATOMIC_RELAXED, __HIP_MEMORY_SCOPE_AGENT);
    // no trailing barrier: barrier F of step s+1 protects Zsh/xsh; flag order
    // certifies all peers' step-s reads completed before buffer reuse.
  }
}

// ---- p = hfin @ W_ph + b_p ; out = log_softmax(p) ----
__global__ void __launch_bounds__(256)
classify_kernel(const float* __restrict__ hfin, const float* __restrict__ Wph,
                const float* __restrict__ bp, float* __restrict__ out) {
  __shared__ float red[256 * 10];
  const int b = blockIdx.x, tid = threadIdx.x;
  float acc[10];
#pragma unroll
  for (int c = 0; c < 10; ++c) acc[c] = 0.f;
  for (int k = tid; k < H_; k += 256) {
    const float hv = hfin[b * H_ + k];
    const float* w = Wph + k * 10;
#pragma unroll
    for (int c = 0; c < 10; ++c) acc[c] += hv * w[c];
  }
#pragma unroll
  for (int c = 0; c < 10; ++c) red[tid * 10 + c] = acc[c];
  __syncthreads();
  for (int off = 128; off >= 1; off >>= 1) {
    if (tid < off) {
#pragma unroll
      for (int c = 0; c < 10; ++c) red[tid * 10 + c] += red[(tid + off) * 10 + c];
    }
    __syncthreads();
  }
  if (tid == 0) {
    float p[10];
    float m = -1e30f;
#pragma unroll
    for (int c = 0; c < 10; ++c) { p[c] = red[c] + bp[c]; m = fmaxf(m, p[c]); }
    float ssum = 0.f;
#pragma unroll
    for (int c = 0; c < 10; ++c) ssum += __expf(p[c] - m);
    const float lse = m + __logf(ssum);
#pragma unroll
    for (int c = 0; c < 10; ++c) out[b * 10 + c] = p[c] - lse;
  }
}

extern "C" void kernel_launch(void* const* d_in, const int* in_sizes, int n_in,
                              void* d_out, int out_size, void* d_ws, size_t ws_size,
                              hipStream_t stream) {
  (void)in_sizes; (void)n_in; (void)out_size; (void)ws_size;
  const int* x = (const int*)d_in[0];
  const float* emb = (const float*)d_in[1];
  const float* Wgx = (const float*)d_in[2];
  const float* Wgh = (const float*)d_in[3];
  const float* bg = (const float*)d_in[4];
  const float* Wix = (const float*)d_in[5];
  const float* Wih = (const float*)d_in[6];
  const float* bi = (const float*)d_in[7];
  const float* Wfx = (const float*)d_in[8];
  const float* Wfh = (const float*)d_in[9];
  const float* bf_ = (const float*)d_in[10];
  const float* Wox = (const float*)d_in[11];
  const float* Woh = (const float*)d_in[12];
  const float* bo = (const float*)d_in[13];
  const float* Wph = (const float*)d_in[14];
  const float* bp = (const float*)d_in[15];
  float* out = (float*)d_out;

  char* ws = (char*)d_ws;
  float* tokproj = (float*)ws;                                  // 2 MB
  unsigned short* WhT = (unsigned short*)(ws + 2097152);        // 8 MB
  unsigned short* hX = (unsigned short*)(ws + 10485760);        // 512 KB (2 bufs)
  float* hfin = (float*)(ws + 11010048);                        // 512 KB
  int* xT = (int*)(ws + 11538432);                              // 256 KB
  unsigned* pub = (unsigned*)(ws + 11800576);                   // 32 KB flags

  (void)hipMemsetAsync(pub, 0, 32768, stream);
  (void)hipFuncSetAttribute(reinterpret_cast<const void*>(lstm_scan),
                            hipFuncAttributeMaxDynamicSharedMemorySize, SMEM_TOTAL);

  prep_kernel<<<dim3(6400), dim3(256), 0, stream>>>(
      emb, Wgx, Wix, Wfx, Wox, bg, bi, bf_, bo,
      Wgh, Wih, Wfh, Woh, x, tokproj, WhT, xT);
  lstm_scan<<<dim3(256), dim3(512), SMEM_TOTAL, stream>>>(
      xT, tokproj, WhT, hX, hfin, pub);
  classify_kernel<<<dim3(128), dim3(256), 0, stream>>>(hfin, Wph, bp, out);
}

// Round 12
// 1612.779 us; speedup vs baseline: 1.1956x; 1.0393x over previous
//
#include <hip/hip_runtime.h>

#define H_ 1024
#define B_ 128
#define S_ 512
#define V_ 128
#define E_ 256

// LDS layout (bytes)
// Zsh: [8 w8][16 row][33 hu-slots][4 gates] f32  (pad 33 breaks bank aliasing)
// tsh: [128 v][33 hu-slots][4 gates] f32
#define ZSH_OFF 0            // 67584
#define TSH_OFF 67584        // 67584
#define XSH_OFF 135168       // 64     int[16] tokens
#define SMEM_TOTAL 135232

#define HXBUF 131072         // ushorts per hX buffer (256 blocks * 512); 3 bufs

typedef __bf16 bf16x8 __attribute__((ext_vector_type(8)));
typedef float f32x4 __attribute__((ext_vector_type(4)));
typedef unsigned long long ull;

#define NANP 0xFFFFFFFFu                  // dword of two bf16 NaNs (0xFFFF)
#define NAN8 0xFFFFFFFFFFFFFFFFull

// Coherent (device-scope, L1/L2-bypass) 16-B load.
// NOTE: inline-asm loads are NOT waitcnt-tracked by the compiler; every use
// of the result must be preceded by an explicit s_waitcnt vmcnt (R8 lesson).
__device__ __forceinline__ uint4 cload16(const unsigned short* p) {
  uint4 r;
  asm volatile("global_load_dwordx4 %0, %1, off sc0 sc1"
               : "=v"(r) : "v"(p) : "memory");
  return r;
}
// Coherent 8-B store via compiler atomics (proven protocol; 8B-atomic).
__device__ __forceinline__ void cstore8(unsigned short* p, ull v) {
  __hip_atomic_store((ull*)p, v, __ATOMIC_RELAXED, __HIP_MEMORY_SCOPE_AGENT);
}

__device__ __forceinline__ unsigned short f2bf(float f) {
  unsigned u = __float_as_uint(f);
  u += 0x7fffu + ((u >> 16) & 1u);   // round-to-nearest-even
  return (unsigned short)(u >> 16);
}
__device__ __forceinline__ float sigf(float x) { return 1.0f / (1.0f + __expf(-x)); }
__device__ __forceinline__ float tanhfast(float x) { return 1.0f - 2.0f / (1.0f + __expf(2.0f * x)); }

// ---- fused prep: tokproj (bid<2048) | WhT (bid<6144) | xpose (bid<6400) ----
__global__ void __launch_bounds__(256)
prep_kernel(const float* __restrict__ emb,
            const float* __restrict__ Wgx, const float* __restrict__ Wix,
            const float* __restrict__ Wfx, const float* __restrict__ Wox,
            const float* __restrict__ bg, const float* __restrict__ bi,
            const float* __restrict__ bf_, const float* __restrict__ bo,
            const float* __restrict__ Wgh, const float* __restrict__ Wih,
            const float* __restrict__ Wfh, const float* __restrict__ Woh,
            const int* __restrict__ x,
            float* __restrict__ tokproj, unsigned short* __restrict__ WhT,
            int* __restrict__ xT) {
  __shared__ float esh[E_];
  const int bid = blockIdx.x;
  if (bid < 2048) {
    const int v = bid >> 4;
    const int c = (bid & 15) * 256 + threadIdx.x;
    const int gate = c >> 10;
    const int j = c & 1023;
    const float* W = (gate == 0) ? Wgx : (gate == 1) ? Wix : (gate == 2) ? Wfx : Wox;
    const float* bias = (gate == 0) ? bg : (gate == 1) ? bi : (gate == 2) ? bf_ : bo;
    esh[threadIdx.x] = emb[v * E_ + threadIdx.x];
    __syncthreads();
    float acc = bias[j];
#pragma unroll 4
    for (int e = 0; e < E_; ++e) acc += esh[e] * W[e * H_ + j];
    tokproj[v * 4096 + c] = acc;
  } else if (bid < 6144) {
    const int c = bid - 2048;
    const int gate = c >> 10;
    const int j = c & 1023;
    const float* W = (gate == 0) ? Wgh : (gate == 1) ? Wih : (gate == 2) ? Wfh : Woh;
    for (int k = threadIdx.x; k < H_; k += 256)
      WhT[c * H_ + k] = f2bf(W[k * H_ + j]);
  } else {
    const int id = (bid - 6144) * 256 + threadIdx.x;  // 65536
    const int s = id >> 7, b = id & 127;
    xT[s * 128 + b] = x[b * S_ + s];
  }
}

// ---- persistent scan: 256 blocks x 512 thr (1 per CU) ----
// R12: flag-hinted NaN-validation, DRAIN-FREE publish (R11 + R9 machinery).
//   Flag is a discovery HINT (fire-and-forget after barrier H); data arrival
//   is certified by the consumer's NaN-tag check (R9-proven). 3-buffer
//   rotation; NaN-reset of slot (s+2)%3 issued fire-and-forget after barrier F
//   (R10's certification: barrier F => all peers' flags >= s+1 => peers done
//   reading that slot). Reset-before-next-data ordering is FREE: the lane's
//   own step-(s+1) probe executes s_waitcnt vmcnt(0), completing the reset
//   before the step-(s+1) data stores/flag are issued => a consumer that sees
//   flag s+2 can only see NaN-or-fresh in any slot it polls. No vmcnt drain
//   anywhere in the steady-state loop (saves ~700cy/step off barrier-H exit).
__global__ void __launch_bounds__(512, 1)
lstm_scan(const int* __restrict__ xT, const float* __restrict__ tokproj,
          const unsigned short* __restrict__ WhT,
          unsigned short* __restrict__ hX, float* __restrict__ hfin,
          unsigned* __restrict__ pub) {
  extern __shared__ char smem[];
  float* Zsh = (float*)(smem + ZSH_OFF);
  float* tsh = (float*)(smem + TSH_OFF);
  int* xsh = (int*)(smem + XSH_OFF);

  const int bid = blockIdx.x;
  const int rg = bid >> 5;
  const int cg = bid & 31;
  const int tid = threadIdx.x;
  const int w = tid >> 6;          // k-slice owner: k in [w*128, +128)
  const int lane = tid & 63;
  const int l15 = lane & 15;
  const int lq = lane >> 4;

  // ---- one-time: tokproj slice -> LDS as [v][hu][gate] ----
  for (int it = tid; it < 16384; it += 512) {
    const int v = it >> 7, j = it & 127;
    const int gate = j >> 5, hu = j & 31;
    tsh[(v * 33 + hu) * 4 + gate] = tokproj[v * 4096 + gate * 1024 + cg * 32 + hu];
  }
  // ---- one-time: B fragments -> registers ----
  uint4 breg[32];
#pragma unroll
  for (int kc = 0; kc < 4; ++kc) {
#pragma unroll
    for (int t = 0; t < 8; ++t) {
      const int j = t * 16 + l15;
      const int c = ((j >> 5) << 10) + cg * 32 + (j & 31);
      breg[kc * 8 + t] =
          *(const uint4*)(WhT + c * 1024 + (w * 4 + kc) * 32 + lq * 8);
    }
  }

  const int row_own = tid >> 5;      // 0..15
  const int hu = tid & 31;           // 0..31
  const int brow = rg * 16 + row_own;
  const int colg = cg * 32 + hu;

  // poll binding: lane polls producer w*4 + (lane&3) (block-level flags)
  const unsigned* myflag = pub + (rg * 32 + w * 4 + (lane & 3)) * 32;
  // fragment bases: producer w*4+kc's slice, this lane's 16B chunk (= lane)
  const unsigned short* abase[4];
#pragma unroll
  for (int kc = 0; kc < 4; ++kc)
    abase[kc] = hX + (rg * 32 + w * 4 + kc) * 512 + lane * 8;

  // publish binding (R11-proven): lanes l%4==0 store 8B chunks; ushort offset
  // within the slice = (prow + (hu0>>3)*16)*8 + (hu0&7)
  const int prow = 2 * w + (lane >> 5);
  const int hu0 = lane & 31;
  const int choff = (prow + ((hu0 >> 3) << 4)) * 8 + (hu0 & 7);

  float creg = 0.f;
  // init: zero own h^0 slice in buf 0 (proven form, once-only drain+flag).
  // Host memset(0xFF) NaN-tagged all 3 bufs; zeros are valid data.
  if (tid < 128) cstore8(hX + bid * 512 + tid * 4, 0ull);
  asm volatile("s_waitcnt vmcnt(0)" ::: "memory");
  __syncthreads();
  if (tid == 0)
    __hip_atomic_store(pub + bid * 32, 1u, __ATOMIC_RELAXED, __HIP_MEMORY_SCOPE_AGENT);

  int bcur = 0;                       // s%3 ; bnxt=(s+1)%3 ; brst=(s+2)%3
  int bnxt = 1;
  int brst = 2;

  for (int s = 0; s < S_; ++s) {
    int xv = 0;
    if (tid < 16) xv = xT[s * 128 + rg * 16 + tid];

    // ---- discovery hint: block flags (cheap 4B polls) ----
    const unsigned tgt = (unsigned)(s + 1);
    while (__hip_atomic_load(myflag, __ATOMIC_RELAXED, __HIP_MEMORY_SCOPE_AGENT) < tgt)
      __builtin_amdgcn_s_sleep(1);

    // ---- NaN-validating probe (R9-proven): certifies data ARRIVAL ----
    // (this vmcnt(0) also completes our own prior-step fire-forget stores,
    //  providing the reset-before-next-data ordering for free)
    const int soff = bcur * HXBUF;
    uint4 a[4];
    {
      int need0 = 1, need1 = 1, need2 = 1, need3 = 1;
      int guard = 0;
      for (;;) {
        if (need0) a[0] = cload16(abase[0] + soff);
        if (need1) a[1] = cload16(abase[1] + soff);
        if (need2) a[2] = cload16(abase[2] + soff);
        if (need3) a[3] = cload16(abase[3] + soff);
        asm volatile("s_waitcnt vmcnt(0)" ::: "memory");   // REQUIRED (R8)
        if (need0) need0 = !__all((int)((a[0].x != NANP) & (a[0].z != NANP)));
        if (need1) need1 = !__all((int)((a[1].x != NANP) & (a[1].z != NANP)));
        if (need2) need2 = !__all((int)((a[2].x != NANP) & (a[2].z != NANP)));
        if (need3) need3 = !__all((int)((a[3].x != NANP) & (a[3].z != NANP)));
        if (!(need0 | need1 | need2 | need3)) break;
        if (++guard > (1 << 14)) break;   // hang-breaker: finite wrong answer
        __builtin_amdgcn_s_sleep(1);
      }
    }
    __builtin_amdgcn_sched_barrier(0);
    // per-component keep-alive AFTER the waitcnt so MFMAs can't be hoisted
#pragma unroll
    for (int kc = 0; kc < 4; ++kc) {
      asm volatile("" : "+v"(a[kc].x), "+v"(a[kc].y), "+v"(a[kc].z), "+v"(a[kc].w));
    }

    if (tid < 16) xsh[tid] = xv;

    // ---- MFMA: wave covers k [w*128,+128) x all 128 cols ----
    f32x4 acc[8];
#pragma unroll
    for (int t = 0; t < 8; ++t) acc[t] = (f32x4){0.f, 0.f, 0.f, 0.f};
#pragma unroll
    for (int kc = 0; kc < 4; ++kc) {
      const bf16x8 av = __builtin_bit_cast(bf16x8, a[kc]);
#pragma unroll
      for (int t = 0; t < 8; ++t)
        acc[t] = __builtin_amdgcn_mfma_f32_16x16x32_bf16(
            av, __builtin_bit_cast(bf16x8, breg[kc * 8 + t]), acc[t], 0, 0, 0);
    }
    // epilogue: pack per-row gate quads -> 2 b128 writes per r_
#pragma unroll
    for (int r_ = 0; r_ < 4; ++r_) {
      const int row = w * 16 + lq * 4 + r_;
      f32x4 lo = {acc[0][r_], acc[2][r_], acc[4][r_], acc[6][r_]};
      f32x4 hi = {acc[1][r_], acc[3][r_], acc[5][r_], acc[7][r_]};
      *(f32x4*)(Zsh + (row * 33 + l15) * 4) = lo;
      *(f32x4*)(Zsh + (row * 33 + l15 + 16) * 4) = hi;
    }
    __syncthreads();   // F  (certifies: all peers' flags >= s+1 observed)

    // ---- EARLY NaN-reset of own chunks in slot brst (fire-and-forget) ----
    if ((lane & 3) == 0)
      cstore8(hX + brst * HXBUF + bid * 512 + choff, NAN8);

    // ---- gate pass + in-register publish pack ----
    {
      const int xb = xsh[row_own];
      f32x4 z4 = *(const f32x4*)(tsh + (xb * 33 + hu) * 4);
#pragma unroll
      for (int w8 = 0; w8 < 8; ++w8)
        z4 += *(const f32x4*)(Zsh + ((w8 * 16 + row_own) * 33 + hu) * 4);
      const float gv = tanhfast(z4[0]);
      const float iv = sigf(z4[1]);
      const float fv = sigf(z4[2]);
      const float ov = sigf(z4[3]);
      creg = gv * iv + creg * fv;
      const float hv = tanhfast(creg) * ov;
      if (s == S_ - 1) hfin[brow * H_ + colg] = hv;

      // pack 4 consecutive hu into 8B: 2 shfl_xor rounds (R11-proven)
      const unsigned hvu = (unsigned)f2bf(hv);
      const unsigned o1 = (unsigned)__shfl_xor((int)hvu, 1);
      const unsigned p01 = (hvu & 0xFFFFu) | (o1 << 16);
      const unsigned o2 = (unsigned)__shfl_xor((int)p01, 2);
      const ull q = (ull)p01 | ((ull)o2 << 32);

      // data store: fire-and-forget (NO drain) — arrival certified by
      // consumers' NaN validation
      if ((lane & 3) == 0)
        cstore8(hX + bnxt * HXBUF + bid * 512 + choff, q);
    }
    __syncthreads();   // H  (all waves ISSUED their stores)
    // flag hint: fire-and-forget, relaxed
    if (tid == 0)
      __hip_atomic_store(pub + bid * 32, (unsigned)(s + 2),
                         __ATOMIC_RELAXED, __HIP_MEMORY_SCOPE_AGENT);

    // rotate buffers
    const int t_ = bcur; bcur = bnxt; bnxt = brst; brst = t_;
  }
}

// ---- p = hfin @ W_ph + b_p ; out = log_softmax(p) ----
__global__ void __launch_bounds__(256)
classify_kernel(const float* __restrict__ hfin, const float* __restrict__ Wph,
                const float* __restrict__ bp, float* __restrict__ out) {
  __shared__ float red[256 * 10];
  const int b = blockIdx.x, tid = threadIdx.x;
  float acc[10];
#pragma unroll
  for (int c = 0; c < 10; ++c) acc[c] = 0.f;
  for (int k = tid; k < H_; k += 256) {
    const float hv = hfin[b * H_ + k];
    const float* w = Wph + k * 10;
#pragma unroll
    for (int c = 0; c < 10; ++c) acc[c] += hv * w[c];
  }
#pragma unroll
  for (int c = 0; c < 10; ++c) red[tid * 10 + c] = acc[c];
  __syncthreads();
  for (int off = 128; off >= 1; off >>= 1) {
    if (tid < off) {
#pragma unroll
      for (int c = 0; c < 10; ++c) red[tid * 10 + c] += red[(tid + off) * 10 + c];
    }
    __syncthreads();
  }
  if (tid == 0) {
    float p[10];
    float m = -1e30f;
#pragma unroll
    for (int c = 0; c < 10; ++c) { p[c] = red[c] + bp[c]; m = fmaxf(m, p[c]); }
    float ssum = 0.f;
#pragma unroll
    for (int c = 0; c < 10; ++c) ssum += __expf(p[c] - m);
    const float lse = m + __logf(ssum);
#pragma unroll
    for (int c = 0; c < 10; ++c) out[b * 10 + c] = p[c] - lse;
  }
}

extern "C" void kernel_launch(void* const* d_in, const int* in_sizes, int n_in,
                              void* d_out, int out_size, void* d_ws, size_t ws_size,
                              hipStream_t stream) {
  (void)in_sizes; (void)n_in; (void)out_size; (void)ws_size;
  const int* x = (const int*)d_in[0];
  const float* emb = (const float*)d_in[1];
  const float* Wgx = (const float*)d_in[2];
  const float* Wgh = (const float*)d_in[3];
  const float* bg = (const float*)d_in[4];
  const float* Wix = (const float*)d_in[5];
  const float* Wih = (const float*)d_in[6];
  const float* bi = (const float*)d_in[7];
  const float* Wfx = (const float*)d_in[8];
  const float* Wfh = (const float*)d_in[9];
  const float* bf_ = (const float*)d_in[10];
  const float* Wox = (const float*)d_in[11];
  const float* Woh = (const float*)d_in[12];
  const float* bo = (const float*)d_in[13];
  const float* Wph = (const float*)d_in[14];
  const float* bp = (const float*)d_in[15];
  float* out = (float*)d_out;

  char* ws = (char*)d_ws;
  float* tokproj = (float*)ws;                                  // 2 MB
  unsigned short* WhT = (unsigned short*)(ws + 2097152);        // 8 MB
  unsigned short* hX = (unsigned short*)(ws + 10485760);        // 768 KB (3 bufs)
  float* hfin = (float*)(ws + 11272192);                        // 512 KB
  int* xT = (int*)(ws + 11796480);                              // 256 KB
  unsigned* pub = (unsigned*)(ws + 12058624);                   // 32 KB flags

  // NaN-tag all 3 h buffers (0xFF bytes -> every bf16 = 0xFFFF = NaN)
  (void)hipMemsetAsync(hX, 0xFF, 786432, stream);
  (void)hipMemsetAsync(pub, 0, 32768, stream);
  (void)hipFuncSetAttribute(reinterpret_cast<const void*>(lstm_scan),
                            hipFuncAttributeMaxDynamicSharedMemorySize, SMEM_TOTAL);

  prep_kernel<<<dim3(6400), dim3(256), 0, stream>>>(
      emb, Wgx, Wix, Wfx, Wox, bg, bi, bf_, bo,
      Wgh, Wih, Wfh, Woh, x, tokproj, WhT, xT);
  lstm_scan<<<dim3(256), dim3(512), SMEM_TOTAL, stream>>>(
      xT, tokproj, WhT, hX, hfin, pub);
  classify_kernel<<<dim3(128), dim3(256), 0, stream>>>(hfin, Wph, bp, out);
}

// Round 14
// 1462.696 us; speedup vs baseline: 1.3182x; 1.1026x over previous
//
#include <hip/hip_runtime.h>

#define H_ 1024
#define B_ 128
#define S_ 512
#define V_ 128
#define E_ 256

// LDS layout (bytes)
// Zsh: [8 w8][16 row][33 hu-slots][4 gates] f32  (pad 33 breaks bank aliasing)
// tsh: [128 v][33 hu-slots][4 gates] f32
#define ZSH_OFF 0            // 67584
#define TSH_OFF 67584        // 67584
#define XSH_OFF 135168       // 64     int[16] tokens
#define SMEM_TOTAL 135232

#define HXBUF 131072         // ushorts per hX buffer (256 blocks * 512); 3 bufs

typedef __bf16 bf16x8 __attribute__((ext_vector_type(8)));
typedef float f32x4 __attribute__((ext_vector_type(4)));
typedef unsigned long long ull;

#define NANP 0xFFFFFFFFu                  // dword of two bf16 NaNs (0xFFFF)
#define NAN8 0xFFFFFFFFFFFFFFFFull

// Coherent (device-scope, L1/L2-bypass) 16-B load.
// NOTE: inline-asm loads are NOT waitcnt-tracked by the compiler; every use
// of the result must be preceded by an explicit s_waitcnt vmcnt (R8 lesson).
__device__ __forceinline__ uint4 cload16(const unsigned short* p) {
  uint4 r;
  asm volatile("global_load_dwordx4 %0, %1, off sc0 sc1"
               : "=v"(r) : "v"(p) : "memory");
  return r;
}
// Coherent 8-B store via compiler atomics (proven protocol; 8B-atomic).
__device__ __forceinline__ void cstore8(unsigned short* p, ull v) {
  __hip_atomic_store((ull*)p, v, __ATOMIC_RELAXED, __HIP_MEMORY_SCOPE_AGENT);
}

__device__ __forceinline__ unsigned short f2bf(float f) {
  unsigned u = __float_as_uint(f);
  u += 0x7fffu + ((u >> 16) & 1u);   // round-to-nearest-even
  return (unsigned short)(u >> 16);
}
__device__ __forceinline__ float sigf(float x) { return 1.0f / (1.0f + __expf(-x)); }
__device__ __forceinline__ float tanhfast(float x) { return 1.0f - 2.0f / (1.0f + __expf(2.0f * x)); }

// ---- fused prep: tokproj (bid<2048) | WhT (bid<6144) | xpose (bid<6400) ----
__global__ void __launch_bounds__(256)
prep_kernel(const float* __restrict__ emb,
            const float* __restrict__ Wgx, const float* __restrict__ Wix,
            const float* __restrict__ Wfx, const float* __restrict__ Wox,
            const float* __restrict__ bg, const float* __restrict__ bi,
            const float* __restrict__ bf_, const float* __restrict__ bo,
            const float* __restrict__ Wgh, const float* __restrict__ Wih,
            const float* __restrict__ Wfh, const float* __restrict__ Woh,
            const int* __restrict__ x,
            float* __restrict__ tokproj, unsigned short* __restrict__ WhT,
            int* __restrict__ xT) {
  __shared__ float esh[E_];
  const int bid = blockIdx.x;
  if (bid < 2048) {
    const int v = bid >> 4;
    const int c = (bid & 15) * 256 + threadIdx.x;
    const int gate = c >> 10;
    const int j = c & 1023;
    const float* W = (gate == 0) ? Wgx : (gate == 1) ? Wix : (gate == 2) ? Wfx : Wox;
    const float* bias = (gate == 0) ? bg : (gate == 1) ? bi : (gate == 2) ? bf_ : bo;
    esh[threadIdx.x] = emb[v * E_ + threadIdx.x];
    __syncthreads();
    float acc = bias[j];
#pragma unroll 4
    for (int e = 0; e < E_; ++e) acc += esh[e] * W[e * H_ + j];
    tokproj[v * 4096 + c] = acc;
  } else if (bid < 6144) {
    const int c = bid - 2048;
    const int gate = c >> 10;
    const int j = c & 1023;
    const float* W = (gate == 0) ? Wgh : (gate == 1) ? Wih : (gate == 2) ? Wfh : Woh;
    for (int k = threadIdx.x; k < H_; k += 256)
      WhT[c * H_ + k] = f2bf(W[k * H_ + j]);
  } else {
    const int id = (bid - 6144) * 256 + threadIdx.x;  // 65536
    const int s = id >> 7, b = id & 127;
    xT[s * 128 + b] = x[b * S_ + s];
  }
}

// ---- persistent scan: 256 blocks x 512 thr (1 per CU) ----
// R14 = R12 (proven) with the flag store moved from post-barrier-H to
// post-barrier-F. The flag's certification content — "all my waves passed
// their ingest vmcnt(0), hence my prior-step NaN-resets LANDED and my
// prior-step reads completed" — is established at barrier F, not H. Consumers
// still gate on the flag (this is what R13 dropped, unsoundly: without it a
// fast consumer's lead vs RESET VISIBILITY is unbounded -> stale reads ->
// early resets clobber peers' fresh data -> NaN). After the gate, the NaN
// probe waits for data arrival (publish is fire-and-forget mid-gate-phase);
// retries are flag-bounded + guarded. Net: discovery starts ~1 phase earlier,
// data-wait overlaps the producer's gate phase.
__global__ void __launch_bounds__(512, 1)
lstm_scan(const int* __restrict__ xT, const float* __restrict__ tokproj,
          const unsigned short* __restrict__ WhT,
          unsigned short* __restrict__ hX, float* __restrict__ hfin,
          unsigned* __restrict__ pub) {
  extern __shared__ char smem[];
  float* Zsh = (float*)(smem + ZSH_OFF);
  float* tsh = (float*)(smem + TSH_OFF);
  int* xsh = (int*)(smem + XSH_OFF);

  const int bid = blockIdx.x;
  const int rg = bid >> 5;
  const int cg = bid & 31;
  const int tid = threadIdx.x;
  const int w = tid >> 6;          // k-slice owner: k in [w*128, +128)
  const int lane = tid & 63;
  const int l15 = lane & 15;
  const int lq = lane >> 4;

  // ---- one-time: tokproj slice -> LDS as [v][hu][gate] ----
  for (int it = tid; it < 16384; it += 512) {
    const int v = it >> 7, j = it & 127;
    const int gate = j >> 5, hu = j & 31;
    tsh[(v * 33 + hu) * 4 + gate] = tokproj[v * 4096 + gate * 1024 + cg * 32 + hu];
  }
  // ---- one-time: B fragments -> registers ----
  uint4 breg[32];
#pragma unroll
  for (int kc = 0; kc < 4; ++kc) {
#pragma unroll
    for (int t = 0; t < 8; ++t) {
      const int j = t * 16 + l15;
      const int c = ((j >> 5) << 10) + cg * 32 + (j & 31);
      breg[kc * 8 + t] =
          *(const uint4*)(WhT + c * 1024 + (w * 4 + kc) * 32 + lq * 8);
    }
  }

  const int row_own = tid >> 5;      // 0..15
  const int hu = tid & 31;           // 0..31
  const int brow = rg * 16 + row_own;
  const int colg = cg * 32 + hu;

  // poll binding: lane polls producer w*4 + (lane&3) (block-level flags)
  const unsigned* myflag = pub + (rg * 32 + w * 4 + (lane & 3)) * 32;
  // fragment bases: producer w*4+kc's slice, this lane's 16B chunk (= lane)
  const unsigned short* abase[4];
#pragma unroll
  for (int kc = 0; kc < 4; ++kc)
    abase[kc] = hX + (rg * 32 + w * 4 + kc) * 512 + lane * 8;

  // publish binding (R11-proven): lanes l%4==0 store 8B chunks; ushort offset
  // within the slice = (prow + (hu0>>3)*16)*8 + (hu0&7)
  const int prow = 2 * w + (lane >> 5);
  const int hu0 = lane & 31;
  const int choff = (prow + ((hu0 >> 3) << 4)) * 8 + (hu0 & 7);

  float creg = 0.f;
  // init: zero own h^0 slice in buf 0 (proven form, once-only drain+flag).
  // Host memset(0xFF) NaN-tagged all 3 bufs; zeros are valid data.
  if (tid < 128) cstore8(hX + bid * 512 + tid * 4, 0ull);
  asm volatile("s_waitcnt vmcnt(0)" ::: "memory");
  __syncthreads();
  if (tid == 0)
    __hip_atomic_store(pub + bid * 32, 1u, __ATOMIC_RELAXED, __HIP_MEMORY_SCOPE_AGENT);

  int bcur = 0;                       // s%3 ; bnxt=(s+1)%3 ; brst=(s+2)%3
  int bnxt = 1;
  int brst = 2;

  for (int s = 0; s < S_; ++s) {
    int xv = 0;
    if (tid < 16) xv = xT[s * 128 + rg * 16 + tid];

    // ---- flag gate (REQUIRED: certifies peers' resets landed + bounds skew) ----
    const unsigned tgt = (unsigned)(s + 1);
    while (__hip_atomic_load(myflag, __ATOMIC_RELAXED, __HIP_MEMORY_SCOPE_AGENT) < tgt)
      __builtin_amdgcn_s_sleep(1);

    // ---- NaN-validating probe: waits for data ARRIVAL (R9-proven check) ----
    // (the vmcnt(0) also completes our own prior fire-forget stores,
    //  giving reset-before-next-data ordering for free)
    const int soff = bcur * HXBUF;
    uint4 a[4];
    {
      int need0 = 1, need1 = 1, need2 = 1, need3 = 1;
      int guard = 0;
      for (;;) {
        if (need0) a[0] = cload16(abase[0] + soff);
        if (need1) a[1] = cload16(abase[1] + soff);
        if (need2) a[2] = cload16(abase[2] + soff);
        if (need3) a[3] = cload16(abase[3] + soff);
        asm volatile("s_waitcnt vmcnt(0)" ::: "memory");   // REQUIRED (R8)
        if (need0) need0 = !__all((int)((a[0].x != NANP) & (a[0].z != NANP)));
        if (need1) need1 = !__all((int)((a[1].x != NANP) & (a[1].z != NANP)));
        if (need2) need2 = !__all((int)((a[2].x != NANP) & (a[2].z != NANP)));
        if (need3) need3 = !__all((int)((a[3].x != NANP) & (a[3].z != NANP)));
        if (!(need0 | need1 | need2 | need3)) break;
        if (++guard > (1 << 14)) break;   // hang-breaker: finite wrong answer
        __builtin_amdgcn_s_sleep(1);
      }
    }
    __builtin_amdgcn_sched_barrier(0);
    // per-component keep-alive AFTER the waitcnt so MFMAs can't be hoisted
#pragma unroll
    for (int kc = 0; kc < 4; ++kc) {
      asm volatile("" : "+v"(a[kc].x), "+v"(a[kc].y), "+v"(a[kc].z), "+v"(a[kc].w));
    }

    if (tid < 16) xsh[tid] = xv;

    // ---- MFMA: wave covers k [w*128,+128) x all 128 cols ----
    f32x4 acc[8];
#pragma unroll
    for (int t = 0; t < 8; ++t) acc[t] = (f32x4){0.f, 0.f, 0.f, 0.f};
#pragma unroll
    for (int kc = 0; kc < 4; ++kc) {
      const bf16x8 av = __builtin_bit_cast(bf16x8, a[kc]);
#pragma unroll
      for (int t = 0; t < 8; ++t)
        acc[t] = __builtin_amdgcn_mfma_f32_16x16x32_bf16(
            av, __builtin_bit_cast(bf16x8, breg[kc * 8 + t]), acc[t], 0, 0, 0);
    }
    // epilogue: pack per-row gate quads -> 2 b128 writes per r_
#pragma unroll
    for (int r_ = 0; r_ < 4; ++r_) {
      const int row = w * 16 + lq * 4 + r_;
      f32x4 lo = {acc[0][r_], acc[2][r_], acc[4][r_], acc[6][r_]};
      f32x4 hi = {acc[1][r_], acc[3][r_], acc[5][r_], acc[7][r_]};
      *(f32x4*)(Zsh + (row * 33 + l15) * 4) = lo;
      *(f32x4*)(Zsh + (row * 33 + l15 + 16) * 4) = hi;
    }
    __syncthreads();   // F  (all waves passed ingest vmcnt(0) -> resets landed)

    // ---- EARLY flag store (moved from post-H): certification is complete
    //      at barrier F; consumers overlap their data-wait with our gate phase
    if (tid == 0)
      __hip_atomic_store(pub + bid * 32, (unsigned)(s + 2),
                         __ATOMIC_RELAXED, __HIP_MEMORY_SCOPE_AGENT);

    // ---- EARLY NaN-reset of own chunks in slot brst (fire-and-forget) ----
    if ((lane & 3) == 0)
      cstore8(hX + brst * HXBUF + bid * 512 + choff, NAN8);

    // ---- gate pass + in-register publish pack ----
    {
      const int xb = xsh[row_own];
      f32x4 z4 = *(const f32x4*)(tsh + (xb * 33 + hu) * 4);
#pragma unroll
      for (int w8 = 0; w8 < 8; ++w8)
        z4 += *(const f32x4*)(Zsh + ((w8 * 16 + row_own) * 33 + hu) * 4);
      const float gv = tanhfast(z4[0]);
      const float iv = sigf(z4[1]);
      const float fv = sigf(z4[2]);
      const float ov = sigf(z4[3]);
      creg = gv * iv + creg * fv;
      const float hv = tanhfast(creg) * ov;
      if (s == S_ - 1) hfin[brow * H_ + colg] = hv;

      // pack 4 consecutive hu into 8B: 2 shfl_xor rounds (R11-proven)
      const unsigned hvu = (unsigned)f2bf(hv);
      const unsigned o1 = (unsigned)__shfl_xor((int)hvu, 1);
      const unsigned p01 = (hvu & 0xFFFFu) | (o1 << 16);
      const unsigned o2 = (unsigned)__shfl_xor((int)p01, 2);
      const ull q = (ull)p01 | ((ull)o2 << 32);

      // data store: fire-and-forget (NO drain) — arrival certified by
      // consumers' NaN validation
      if ((lane & 3) == 0)
        cstore8(hX + bnxt * HXBUF + bid * 512 + choff, q);
    }
    __syncthreads();   // H  (protects xsh/Zsh against next-step overwrites)

    // rotate buffers
    const int t_ = bcur; bcur = bnxt; bnxt = brst; brst = t_;
  }
}

// ---- p = hfin @ W_ph + b_p ; out = log_softmax(p) ----
__global__ void __launch_bounds__(256)
classify_kernel(const float* __restrict__ hfin, const float* __restrict__ Wph,
                const float* __restrict__ bp, float* __restrict__ out) {
  __shared__ float red[256 * 10];
  const int b = blockIdx.x, tid = threadIdx.x;
  float acc[10];
#pragma unroll
  for (int c = 0; c < 10; ++c) acc[c] = 0.f;
  for (int k = tid; k < H_; k += 256) {
    const float hv = hfin[b * H_ + k];
    const float* w = Wph + k * 10;
#pragma unroll
    for (int c = 0; c < 10; ++c) acc[c] += hv * w[c];
  }
#pragma unroll
  for (int c = 0; c < 10; ++c) red[tid * 10 + c] = acc[c];
  __syncthreads();
  for (int off = 128; off >= 1; off >>= 1) {
    if (tid < off) {
#pragma unroll
      for (int c = 0; c < 10; ++c) red[tid * 10 + c] += red[(tid + off) * 10 + c];
    }
    __syncthreads();
  }
  if (tid == 0) {
    float p[10];
    float m = -1e30f;
#pragma unroll
    for (int c = 0; c < 10; ++c) { p[c] = red[c] + bp[c]; m = fmaxf(m, p[c]); }
    float ssum = 0.f;
#pragma unroll
    for (int c = 0; c < 10; ++c) ssum += __expf(p[c] - m);
    const float lse = m + __logf(ssum);
#pragma unroll
    for (int c = 0; c < 10; ++c) out[b * 10 + c] = p[c] - lse;
  }
}

extern "C" void kernel_launch(void* const* d_in, const int* in_sizes, int n_in,
                              void* d_out, int out_size, void* d_ws, size_t ws_size,
                              hipStream_t stream) {
  (void)in_sizes; (void)n_in; (void)out_size; (void)ws_size;
  const int* x = (const int*)d_in[0];
  const float* emb = (const float*)d_in[1];
  const float* Wgx = (const float*)d_in[2];
  const float* Wgh = (const float*)d_in[3];
  const float* bg = (const float*)d_in[4];
  const float* Wix = (const float*)d_in[5];
  const float* Wih = (const float*)d_in[6];
  const float* bi = (const float*)d_in[7];
  const float* Wfx = (const float*)d_in[8];
  const float* Wfh = (const float*)d_in[9];
  const float* bf_ = (const float*)d_in[10];
  const float* Wox = (const float*)d_in[11];
  const float* Woh = (const float*)d_in[12];
  const float* bo = (const float*)d_in[13];
  const float* Wph = (const float*)d_in[14];
  const float* bp = (const float*)d_in[15];
  float* out = (float*)d_out;

  char* ws = (char*)d_ws;
  float* tokproj = (float*)ws;                                  // 2 MB
  unsigned short* WhT = (unsigned short*)(ws + 2097152);        // 8 MB
  unsigned short* hX = (unsigned short*)(ws + 10485760);        // 768 KB (3 bufs)
  float* hfin = (float*)(ws + 11272192);                        // 512 KB
  int* xT = (int*)(ws + 11796480);                              // 256 KB
  unsigned* pub = (unsigned*)(ws + 12058624);                   // 32 KB flags

  // NaN-tag all 3 h buffers (0xFF bytes -> every bf16 = 0xFFFF = NaN)
  (void)hipMemsetAsync(hX, 0xFF, 786432, stream);
  (void)hipMemsetAsync(pub, 0, 32768, stream);
  (void)hipFuncSetAttribute(reinterpret_cast<const void*>(lstm_scan),
                            hipFuncAttributeMaxDynamicSharedMemorySize, SMEM_TOTAL);

  prep_kernel<<<dim3(6400), dim3(256), 0, stream>>>(
      emb, Wgx, Wix, Wfx, Wox, bg, bi, bf_, bo,
      Wgh, Wih, Wfh, Woh, x, tokproj, WhT, xT);
  lstm_scan<<<dim3(256), dim3(512), SMEM_TOTAL, stream>>>(
      xT, tokproj, WhT, hX, hfin, pub);
  classify_kernel<<<dim3(128), dim3(256), 0, stream>>>(hfin, Wph, bp, out);
}

// Round 16
// 1449.483 us; speedup vs baseline: 1.3302x; 1.0091x over previous
//
#include <hip/hip_runtime.h>

#define H_ 1024
#define B_ 128
#define S_ 512
#define V_ 128
#define E_ 256

// LDS layout (bytes)
// Zsh: [8 w8][16 row][33 hu-slots][4 gates] f32  (pad 33 breaks bank aliasing)
// tsh: [128 v][33 hu-slots][4 gates] f32
#define ZSH_OFF 0            // 67584
#define TSH_OFF 67584        // 67584
#define XSH_OFF 135168       // 64     int[16] tokens
#define SMEM_TOTAL 135232

#define HXBUF 131072         // ushorts per hX buffer (256 blocks * 512); 3 bufs

typedef __bf16 bf16x8 __attribute__((ext_vector_type(8)));
typedef float f32x4 __attribute__((ext_vector_type(4)));
typedef unsigned long long ull;

#define NANP 0xFFFFFFFFu                  // dword of two bf16 NaNs (0xFFFF)
#define NAN8 0xFFFFFFFFFFFFFFFFull

// Coherent (device-scope, L1/L2-bypass) 16-B load.
// NOTE: inline-asm loads are NOT waitcnt-tracked by the compiler; every use
// of the result must be preceded by an explicit s_waitcnt vmcnt IN THE SAME
// straight-line region (R8 lesson). Never carry asm-defined load results
// across a loop back-edge (R15 lesson: regalloc back-edge copies can read
// in-flight destinations before the next iteration's vmcnt).
__device__ __forceinline__ uint4 cload16(const unsigned short* p) {
  uint4 r;
  asm volatile("global_load_dwordx4 %0, %1, off sc0 sc1"
               : "=v"(r) : "v"(p) : "memory");
  return r;
}
// Coherent 8-B store via compiler atomics (proven protocol; 8B-atomic).
__device__ __forceinline__ void cstore8(unsigned short* p, ull v) {
  __hip_atomic_store((ull*)p, v, __ATOMIC_RELAXED, __HIP_MEMORY_SCOPE_AGENT);
}

__device__ __forceinline__ unsigned short f2bf(float f) {
  unsigned u = __float_as_uint(f);
  u += 0x7fffu + ((u >> 16) & 1u);   // round-to-nearest-even
  return (unsigned short)(u >> 16);
}
__device__ __forceinline__ float sigf(float x) { return 1.0f / (1.0f + __expf(-x)); }
__device__ __forceinline__ float tanhfast(float x) { return 1.0f - 2.0f / (1.0f + __expf(2.0f * x)); }

// ---- fused prep: tokproj (bid<2048) | WhT (bid<6144) | xpose (bid<6400) ----
__global__ void __launch_bounds__(256)
prep_kernel(const float* __restrict__ emb,
            const float* __restrict__ Wgx, const float* __restrict__ Wix,
            const float* __restrict__ Wfx, const float* __restrict__ Wox,
            const float* __restrict__ bg, const float* __restrict__ bi,
            const float* __restrict__ bf_, const float* __restrict__ bo,
            const float* __restrict__ Wgh, const float* __restrict__ Wih,
            const float* __restrict__ Wfh, const float* __restrict__ Woh,
            const int* __restrict__ x,
            float* __restrict__ tokproj, unsigned short* __restrict__ WhT,
            int* __restrict__ xT) {
  __shared__ float esh[E_];
  const int bid = blockIdx.x;
  if (bid < 2048) {
    const int v = bid >> 4;
    const int c = (bid & 15) * 256 + threadIdx.x;
    const int gate = c >> 10;
    const int j = c & 1023;
    const float* W = (gate == 0) ? Wgx : (gate == 1) ? Wix : (gate == 2) ? Wfx : Wox;
    const float* bias = (gate == 0) ? bg : (gate == 1) ? bi : (gate == 2) ? bf_ : bo;
    esh[threadIdx.x] = emb[v * E_ + threadIdx.x];
    __syncthreads();
    float acc = bias[j];
#pragma unroll 4
    for (int e = 0; e < E_; ++e) acc += esh[e] * W[e * H_ + j];
    tokproj[v * 4096 + c] = acc;
  } else if (bid < 6144) {
    const int c = bid - 2048;
    const int gate = c >> 10;
    const int j = c & 1023;
    const float* W = (gate == 0) ? Wgh : (gate == 1) ? Wih : (gate == 2) ? Wfh : Woh;
    for (int k = threadIdx.x; k < H_; k += 256)
      WhT[c * H_ + k] = f2bf(W[k * H_ + j]);
  } else {
    const int id = (bid - 6144) * 256 + threadIdx.x;  // 65536
    const int s = id >> 7, b = id & 127;
    xT[s * 128 + b] = x[b * S_ + s];
  }
}

// ---- persistent scan: 256 blocks x 512 thr (1 per CU) ----
// R14-final (proven): flag-hinted NaN-validation, drain-free publish, 3-buffer
// rotation, flag store at barrier F. The flag gate certifies peers' NaN-resets
// landed + bounds skew (dropping it — R13 — is unsound: a fast consumer's
// lead vs reset VISIBILITY is unbounded -> stale reads). After the gate, the
// NaN probe waits for data arrival (publish is fire-and-forget mid-gate-phase);
// retries are flag-bounded + guarded. Discovery starts at the producer's
// barrier F; data-wait overlaps the producer's gate phase.
__global__ void __launch_bounds__(512, 1)
lstm_scan(const int* __restrict__ xT, const float* __restrict__ tokproj,
          const unsigned short* __restrict__ WhT,
          unsigned short* __restrict__ hX, float* __restrict__ hfin,
          unsigned* __restrict__ pub) {
  extern __shared__ char smem[];
  float* Zsh = (float*)(smem + ZSH_OFF);
  float* tsh = (float*)(smem + TSH_OFF);
  int* xsh = (int*)(smem + XSH_OFF);

  const int bid = blockIdx.x;
  const int rg = bid >> 5;
  const int cg = bid & 31;
  const int tid = threadIdx.x;
  const int w = tid >> 6;          // k-slice owner: k in [w*128, +128)
  const int lane = tid & 63;
  const int l15 = lane & 15;
  const int lq = lane >> 4;

  // ---- one-time: tokproj slice -> LDS as [v][hu][gate] ----
  for (int it = tid; it < 16384; it += 512) {
    const int v = it >> 7, j = it & 127;
    const int gate = j >> 5, hu = j & 31;
    tsh[(v * 33 + hu) * 4 + gate] = tokproj[v * 4096 + gate * 1024 + cg * 32 + hu];
  }
  // ---- one-time: B fragments -> registers ----
  uint4 breg[32];
#pragma unroll
  for (int kc = 0; kc < 4; ++kc) {
#pragma unroll
    for (int t = 0; t < 8; ++t) {
      const int j = t * 16 + l15;
      const int c = ((j >> 5) << 10) + cg * 32 + (j & 31);
      breg[kc * 8 + t] =
          *(const uint4*)(WhT + c * 1024 + (w * 4 + kc) * 32 + lq * 8);
    }
  }

  const int row_own = tid >> 5;      // 0..15
  const int hu = tid & 31;           // 0..31
  const int brow = rg * 16 + row_own;
  const int colg = cg * 32 + hu;

  // poll binding: lane polls producer w*4 + (lane&3) (block-level flags)
  const unsigned* myflag = pub + (rg * 32 + w * 4 + (lane & 3)) * 32;
  // fragment bases: producer w*4+kc's slice, this lane's 16B chunk (= lane)
  const unsigned short* abase[4];
#pragma unroll
  for (int kc = 0; kc < 4; ++kc)
    abase[kc] = hX + (rg * 32 + w * 4 + kc) * 512 + lane * 8;

  // publish binding (R11-proven): lanes l%4==0 store 8B chunks; ushort offset
  // within the slice = (prow + (hu0>>3)*16)*8 + (hu0&7)
  const int prow = 2 * w + (lane >> 5);
  const int hu0 = lane & 31;
  const int choff = (prow + ((hu0 >> 3) << 4)) * 8 + (hu0 & 7);

  float creg = 0.f;
  // init: zero own h^0 slice in buf 0 (proven form, once-only drain+flag).
  // Host memset(0xFF) NaN-tagged all 3 bufs; zeros are valid data.
  if (tid < 128) cstore8(hX + bid * 512 + tid * 4, 0ull);
  asm volatile("s_waitcnt vmcnt(0)" ::: "memory");
  __syncthreads();
  if (tid == 0)
    __hip_atomic_store(pub + bid * 32, 1u, __ATOMIC_RELAXED, __HIP_MEMORY_SCOPE_AGENT);

  int bcur = 0;                       // s%3 ; bnxt=(s+1)%3 ; brst=(s+2)%3
  int bnxt = 1;
  int brst = 2;

  for (int s = 0; s < S_; ++s) {
    int xv = 0;
    if (tid < 16) xv = xT[s * 128 + rg * 16 + tid];

    // ---- flag gate (REQUIRED: certifies peers' resets landed + bounds skew) ----
    const unsigned tgt = (unsigned)(s + 1);
    while (__hip_atomic_load(myflag, __ATOMIC_RELAXED, __HIP_MEMORY_SCOPE_AGENT) < tgt)
      __builtin_amdgcn_s_sleep(1);

    // ---- NaN-validating probe: waits for data ARRIVAL (R9-proven check) ----
    // (the vmcnt(0) also completes our own prior fire-forget stores,
    //  giving reset-before-next-data ordering for free)
    const int soff = bcur * HXBUF;
    uint4 a[4];
    {
      int need0 = 1, need1 = 1, need2 = 1, need3 = 1;
      int guard = 0;
      for (;;) {
        if (need0) a[0] = cload16(abase[0] + soff);
        if (need1) a[1] = cload16(abase[1] + soff);
        if (need2) a[2] = cload16(abase[2] + soff);
        if (need3) a[3] = cload16(abase[3] + soff);
        asm volatile("s_waitcnt vmcnt(0)" ::: "memory");   // REQUIRED (R8)
        if (need0) need0 = !__all((int)((a[0].x != NANP) & (a[0].z != NANP)));
        if (need1) need1 = !__all((int)((a[1].x != NANP) & (a[1].z != NANP)));
        if (need2) need2 = !__all((int)((a[2].x != NANP) & (a[2].z != NANP)));
        if (need3) need3 = !__all((int)((a[3].x != NANP) & (a[3].z != NANP)));
        if (!(need0 | need1 | need2 | need3)) break;
        if (++guard > (1 << 14)) break;   // hang-breaker: finite wrong answer
        __builtin_amdgcn_s_sleep(1);
      }
    }
    __builtin_amdgcn_sched_barrier(0);
    // per-component keep-alive AFTER the waitcnt so MFMAs can't be hoisted
#pragma unroll
    for (int kc = 0; kc < 4; ++kc) {
      asm volatile("" : "+v"(a[kc].x), "+v"(a[kc].y), "+v"(a[kc].z), "+v"(a[kc].w));
    }

    if (tid < 16) xsh[tid] = xv;

    // ---- MFMA: wave covers k [w*128,+128) x all 128 cols ----
    f32x4 acc[8];
#pragma unroll
    for (int t = 0; t < 8; ++t) acc[t] = (f32x4){0.f, 0.f, 0.f, 0.f};
#pragma unroll
    for (int kc = 0; kc < 4; ++kc) {
      const bf16x8 av = __builtin_bit_cast(bf16x8, a[kc]);
#pragma unroll
      for (int t = 0; t < 8; ++t)
        acc[t] = __builtin_amdgcn_mfma_f32_16x16x32_bf16(
            av, __builtin_bit_cast(bf16x8, breg[kc * 8 + t]), acc[t], 0, 0, 0);
    }
    // epilogue: pack per-row gate quads -> 2 b128 writes per r_
#pragma unroll
    for (int r_ = 0; r_ < 4; ++r_) {
      const int row = w * 16 + lq * 4 + r_;
      f32x4 lo = {acc[0][r_], acc[2][r_], acc[4][r_], acc[6][r_]};
      f32x4 hi = {acc[1][r_], acc[3][r_], acc[5][r_], acc[7][r_]};
      *(f32x4*)(Zsh + (row * 33 + l15) * 4) = lo;
      *(f32x4*)(Zsh + (row * 33 + l15 + 16) * 4) = hi;
    }
    __syncthreads();   // F  (all waves passed ingest vmcnt(0) -> resets landed)

    // ---- EARLY flag store: certification complete at barrier F; consumers
    //      overlap their data-wait with our gate phase
    if (tid == 0)
      __hip_atomic_store(pub + bid * 32, (unsigned)(s + 2),
                         __ATOMIC_RELAXED, __HIP_MEMORY_SCOPE_AGENT);

    // ---- EARLY NaN-reset of own chunks in slot brst (fire-and-forget) ----
    if ((lane & 3) == 0)
      cstore8(hX + brst * HXBUF + bid * 512 + choff, NAN8);

    // ---- gate pass + in-register publish pack ----
    {
      const int xb = xsh[row_own];
      f32x4 z4 = *(const f32x4*)(tsh + (xb * 33 + hu) * 4);
#pragma unroll
      for (int w8 = 0; w8 < 8; ++w8)
        z4 += *(const f32x4*)(Zsh + ((w8 * 16 + row_own) * 33 + hu) * 4);
      const float gv = tanhfast(z4[0]);
      const float iv = sigf(z4[1]);
      const float fv = sigf(z4[2]);
      const float ov = sigf(z4[3]);
      creg = gv * iv + creg * fv;
      const float hv = tanhfast(creg) * ov;
      if (s == S_ - 1) hfin[brow * H_ + colg] = hv;

      // pack 4 consecutive hu into 8B: 2 shfl_xor rounds (R11-proven)
      const unsigned hvu = (unsigned)f2bf(hv);
      const unsigned o1 = (unsigned)__shfl_xor((int)hvu, 1);
      const unsigned p01 = (hvu & 0xFFFFu) | (o1 << 16);
      const unsigned o2 = (unsigned)__shfl_xor((int)p01, 2);
      const ull q = (ull)p01 | ((ull)o2 << 32);

      // data store: fire-and-forget (NO drain) — arrival certified by
      // consumers' NaN validation
      if ((lane & 3) == 0)
        cstore8(hX + bnxt * HXBUF + bid * 512 + choff, q);
    }
    __syncthreads();   // H  (protects xsh/Zsh against next-step overwrites)

    // rotate buffers
    const int t_ = bcur; bcur = bnxt; bnxt = brst; brst = t_;
  }
}

// ---- p = hfin @ W_ph + b_p ; out = log_softmax(p) ----
__global__ void __launch_bounds__(256)
classify_kernel(const float* __restrict__ hfin, const float* __restrict__ Wph,
                const float* __restrict__ bp, float* __restrict__ out) {
  __shared__ float red[256 * 10];
  const int b = blockIdx.x, tid = threadIdx.x;
  float acc[10];
#pragma unroll
  for (int c = 0; c < 10; ++c) acc[c] = 0.f;
  for (int k = tid; k < H_; k += 256) {
    const float hv = hfin[b * H_ + k];
    const float* w = Wph + k * 10;
#pragma unroll
    for (int c = 0; c < 10; ++c) acc[c] += hv * w[c];
  }
#pragma unroll
  for (int c = 0; c < 10; ++c) red[tid * 10 + c] = acc[c];
  __syncthreads();
  for (int off = 128; off >= 1; off >>= 1) {
    if (tid < off) {
#pragma unroll
      for (int c = 0; c < 10; ++c) red[tid * 10 + c] += red[(tid + off) * 10 + c];
    }
    __syncthreads();
  }
  if (tid == 0) {
    float p[10];
    float m = -1e30f;
#pragma unroll
    for (int c = 0; c < 10; ++c) { p[c] = red[c] + bp[c]; m = fmaxf(m, p[c]); }
    float ssum = 0.f;
#pragma unroll
    for (int c = 0; c < 10; ++c) ssum += __expf(p[c] - m);
    const float lse = m + __logf(ssum);
#pragma unroll
    for (int c = 0; c < 10; ++c) out[b * 10 + c] = p[c] - lse;
  }
}

extern "C" void kernel_launch(void* const* d_in, const int* in_sizes, int n_in,
                              void* d_out, int out_size, void* d_ws, size_t ws_size,
                              hipStream_t stream) {
  (void)in_sizes; (void)n_in; (void)out_size; (void)ws_size;
  const int* x = (const int*)d_in[0];
  const float* emb = (const float*)d_in[1];
  const float* Wgx = (const float*)d_in[2];
  const float* Wgh = (const float*)d_in[3];
  const float* bg = (const float*)d_in[4];
  const float* Wix = (const float*)d_in[5];
  const float* Wih = (const float*)d_in[6];
  const float* bi = (const float*)d_in[7];
  const float* Wfx = (const float*)d_in[8];
  const float* Wfh = (const float*)d_in[9];
  const float* bf_ = (const float*)d_in[10];
  const float* Wox = (const float*)d_in[11];
  const float* Woh = (const float*)d_in[12];
  const float* bo = (const float*)d_in[13];
  const float* Wph = (const float*)d_in[14];
  const float* bp = (const float*)d_in[15];
  float* out = (float*)d_out;

  char* ws = (char*)d_ws;
  float* tokproj = (float*)ws;                                  // 2 MB
  unsigned short* WhT = (unsigned short*)(ws + 2097152);        // 8 MB
  unsigned short* hX = (unsigned short*)(ws + 10485760);        // 768 KB (3 bufs)
  float* hfin = (float*)(ws + 11272192);                        // 512 KB
  int* xT = (int*)(ws + 11796480);                              // 256 KB
  unsigned* pub = (unsigned*)(ws + 12058624);                   // 32 KB flags

  // NaN-tag all 3 h buffers (0xFF bytes -> every bf16 = 0xFFFF = NaN)
  (void)hipMemsetAsync(hX, 0xFF, 786432, stream);
  (void)hipMemsetAsync(pub, 0, 32768, stream);
  (void)hipFuncSetAttribute(reinterpret_cast<const void*>(lstm_scan),
                            hipFuncAttributeMaxDynamicSharedMemorySize, SMEM_TOTAL);

  prep_kernel<<<dim3(6400), dim3(256), 0, stream>>>(
      emb, Wgx, Wix, Wfx, Wox, bg, bi, bf_, bo,
      Wgh, Wih, Wfh, Woh, x, tokproj, WhT, xT);
  lstm_scan<<<dim3(256), dim3(512), SMEM_TOTAL, stream>>>(
      xT, tokproj, WhT, hX, hfin, pub);
  classify_kernel<<<dim3(128), dim3(256), 0, stream>>>(hfin, Wph, bp, out);
}